// Round 1
// baseline (1694.240 us; speedup 1.0000x reference)
//
#include <hip/hip_runtime.h>
#include <hip/hip_bf16.h>

// Problem constants (MinimalEventMamba)
#define BB   4      // batch
#define NBC  5      // num_bins (input channels)
#define HD   64     // hidden dim
#define NLAYER 4
#define NFC  10     // output frames/channels
#define DIM  128    // d_inner
#define DSN  16     // d_state
#define DCN  4      // d_conv
#define DTRK 4      // dt_rank
#define HH   64
#define WWD  64
#define LL   4096   // H*W
#define MM   (BB*LL)   // 16384 sequence rows total
#define NCHUNK 32
#define CLEN   128     // NCHUNK*CLEN == LL

// ---------------- Encoder conv: (B,5,64,64) -> (B,64,64,64) NCHW ----------------
__global__ void k_enc_conv(const float* __restrict__ x, const float* __restrict__ w,
                           const float* __restrict__ bias, float* __restrict__ out) {
    int idx = blockIdx.x * blockDim.x + threadIdx.x;   // (b,co,h,w) = 1048576
    int wx = idx & 63;
    int hy = (idx >> 6) & 63;
    int co = (idx >> 12) & 63;
    int b  = idx >> 18;
    float acc = bias[co];
    for (int ci = 0; ci < NBC; ++ci) {
        const float* xin = x + (((long)(b * NBC + ci)) << 12);
        const float* wp  = w + (co * NBC + ci) * 9;
        #pragma unroll
        for (int kh = 0; kh < 3; ++kh) {
            int ih = hy + kh - 1;
            if (ih < 0 || ih >= HH) continue;
            #pragma unroll
            for (int kw = 0; kw < 3; ++kw) {
                int iw = wx + kw - 1;
                if (iw < 0 || iw >= WWD) continue;
                acc += xin[(ih << 6) + iw] * wp[kh * 3 + kw];
            }
        }
    }
    out[idx] = acc;
}

// ---------------- BatchNorm training-mode stats over (N,H,W), C=64 ----------------
// src layout (B, 64, 4096). mv[0..63]=mean, mv[64..127]=biased var.
__global__ void k_bn_stats(const float* __restrict__ src, float* __restrict__ mv) {
    __shared__ float s1[256];
    __shared__ float s2[256];
    int c = blockIdx.x;
    int tid = threadIdx.x;
    float sum = 0.f, sq = 0.f;
    for (int i = tid; i < BB * LL; i += 256) {
        int b = i >> 12;
        int hw = i & 4095;
        float v = src[((long)((b << 6) + c) << 12) + hw];
        sum += v; sq += v * v;
    }
    s1[tid] = sum; s2[tid] = sq;
    __syncthreads();
    for (int off = 128; off > 0; off >>= 1) {
        if (tid < off) { s1[tid] += s1[tid + off]; s2[tid] += s2[tid + off]; }
        __syncthreads();
    }
    if (tid == 0) {
        float m = s1[0] * (1.f / 16384.f);
        mv[c] = m;
        mv[64 + c] = s2[0] * (1.f / 16384.f) - m * m;
    }
}

// BN+ReLU, writing sequence layout t[b, l, c]  (l = h*64+w)
__global__ void k_bn_apply_seq(const float* __restrict__ src, const float* __restrict__ mv,
                               const float* __restrict__ g, const float* __restrict__ be,
                               float* __restrict__ tout) {
    int idx = blockIdx.x * blockDim.x + threadIdx.x;  // (b,c,hw)
    int hw = idx & 4095;
    int c = (idx >> 12) & 63;
    int b = idx >> 18;
    float v = src[idx];
    float y = (v - mv[c]) * rsqrtf(mv[64 + c] + 1e-5f) * g[c] + be[c];
    y = fmaxf(y, 0.f);
    tout[(((long)(b << 12) + hw) << 6) + c] = y;
}

// BN+ReLU, NCHW in/out (decoder path)
__global__ void k_bn_apply_nchw(const float* __restrict__ src, const float* __restrict__ mv,
                                const float* __restrict__ g, const float* __restrict__ be,
                                float* __restrict__ out) {
    int idx = blockIdx.x * blockDim.x + threadIdx.x;
    int c = (idx >> 12) & 63;
    float v = src[idx];
    float y = (v - mv[c]) * rsqrtf(mv[64 + c] + 1e-5f) * g[c] + be[c];
    out[idx] = fmaxf(y, 0.f);
}

// ---------------- in_proj GEMM: xz[m, n<256] = sum_k t[m,k<64] * W[n,k] ----------------
// 256 threads/block, 8 rows per block staged in LDS, thread n owns column n.
__global__ void k_gemm_in(const float* __restrict__ tin, const float* __restrict__ Wp,
                          float* __restrict__ xz) {
    __shared__ float ts[8][HD];
    int m0 = blockIdx.x * 8;
    int tid = threadIdx.x;
    for (int i = tid; i < 8 * HD; i += 256)
        ts[i >> 6][i & 63] = tin[((long)m0 << 6) + i];
    __syncthreads();
    float acc[8] = {0.f,0.f,0.f,0.f,0.f,0.f,0.f,0.f};
    const float* wr = Wp + tid * HD;
    for (int k = 0; k < HD; ++k) {
        float w = wr[k];
        #pragma unroll
        for (int r = 0; r < 8; ++r) acc[r] += ts[r][k] * w;
    }
    #pragma unroll
    for (int r = 0; r < 8; ++r)
        xz[((long)(m0 + r) << 8) + tid] = acc[r];
}

// ---------------- causal depthwise conv (K=4) + SiLU on xi = xz[..., :128] ----------------
__global__ void k_dwconv_silu(const float* __restrict__ xz, const float* __restrict__ cw,
                              const float* __restrict__ cb, float* __restrict__ xi) {
    int idx = blockIdx.x * blockDim.x + threadIdx.x;   // (b,l,di) = 2097152
    int di = idx & 127;
    int bl = idx >> 7;
    int l = bl & 4095;
    int b = bl >> 12;
    float acc = cb[di];
    #pragma unroll
    for (int k = 0; k < DCN; ++k) {
        int ls = l + k - (DCN - 1);
        if (ls >= 0)
            acc += xz[((((long)b << 12) + ls) << 8) + di] * cw[(di << 2) + k];
    }
    float sig = 1.f / (1.f + expf(-acc));
    xi[idx] = acc * sig;
}

// ---------------- x_proj GEMM: xdbc[m, j<36] = sum_k xi[m,k<128] * W[j,k] ----------------
__global__ void k_gemm_xproj(const float* __restrict__ xi, const float* __restrict__ Wx,
                             float* __restrict__ xdbc) {
    int idx = blockIdx.x * blockDim.x + threadIdx.x;  // MM*36
    if (idx >= MM * 36) return;
    int j = idx % 36;
    long m = idx / 36;
    const float* xr = xi + (m << 7);
    const float* wr = Wx + j * DIM;
    float acc = 0.f;
    for (int k = 0; k < DIM; ++k) acc += xr[k] * wr[k];
    xdbc[idx] = acc;
}

// ---------------- delta = softplus(dt @ dt_w^T + dt_b) ----------------
__global__ void k_dt_softplus(const float* __restrict__ xdbc, const float* __restrict__ dw,
                              const float* __restrict__ dbias, float* __restrict__ delta) {
    int idx = blockIdx.x * blockDim.x + threadIdx.x;  // (b,l,di)
    int di = idx & 127;
    long m = idx >> 7;
    const float* dr = xdbc + m * 36;   // dt = xdbc[:, 0:4]
    float v = dbias[di];
    #pragma unroll
    for (int r = 0; r < DTRK; ++r) v += dr[r] * dw[(di << 2) + r];
    delta[idx] = (v > 20.f) ? v : log1pf(expf(v));
}

// ---------------- selective scan, chunked (3 phases) ----------------
// lane recurrence: h_t = exp(d_t*A)*h_{t-1} + d_t*u_t*B_t  per (b,di,ds)
// phase1: per chunk, starting h=0: store P=prod(a), S=local end state.
__global__ void k_scan_p1(const float* __restrict__ delta, const float* __restrict__ xi,
                          const float* __restrict__ xdbc, const float* __restrict__ A_log,
                          float* __restrict__ Pb, float* __restrict__ Sb) {
    int chunk = blockIdx.x;
    int b = blockIdx.y;
    int dg = blockIdx.z;
    int tid = threadIdx.x;       // 128 = 8 di x 16 ds
    int dl = tid >> 4;
    int ds = tid & 15;
    int di = (dg << 3) + dl;
    float Av = -expf(A_log[(di << 4) + ds]);
    float h = 0.f, P = 1.f;
    long t0 = (long)b * LL + (long)chunk * CLEN;
    for (int tl = 0; tl < CLEN; ++tl) {
        long base = t0 + tl;
        float d = delta[(base << 7) + di];
        float u = xi[(base << 7) + di];
        float Bv = xdbc[base * 36 + DTRK + ds];
        float a = expf(d * Av);
        h = a * h + (d * u) * Bv;
        P *= a;
    }
    long sidx = ((((long)b * DIM + di) << 4) + ds) * NCHUNK + chunk;
    Pb[sidx] = P;
    Sb[sidx] = h;
}

// phase2: stitch chunks (32 sequential steps per lane), store h at chunk entry.
__global__ void k_scan_p2(const float* __restrict__ Pb, const float* __restrict__ Sb,
                          float* __restrict__ hin) {
    int s = blockIdx.x * blockDim.x + threadIdx.x;  // 8192 = B*DI*DS
    long base = (long)s * NCHUNK;
    float h = 0.f;
    for (int c = 0; c < NCHUNK; ++c) {
        hin[base + c] = h;
        h = Pb[base + c] * h + Sb[base + c];
    }
}

// phase3: replay with correct entry state; y = sum_ds h*C (shfl reduce) + u*D;
// fuse gating: gated = y * silu(z).
__global__ void k_scan_p3(const float* __restrict__ delta, const float* __restrict__ xi,
                          const float* __restrict__ xdbc, const float* __restrict__ A_log,
                          const float* __restrict__ Dp, const float* __restrict__ xz,
                          const float* __restrict__ hin, float* __restrict__ gated) {
    int chunk = blockIdx.x;
    int b = blockIdx.y;
    int dg = blockIdx.z;
    int tid = threadIdx.x;
    int dl = tid >> 4;
    int ds = tid & 15;
    int di = (dg << 3) + dl;
    float Av = -expf(A_log[(di << 4) + ds]);
    float Dv = Dp[di];
    float h = hin[((((long)b * DIM + di) << 4) + ds) * NCHUNK + chunk];
    long t0 = (long)b * LL + (long)chunk * CLEN;
    for (int tl = 0; tl < CLEN; ++tl) {
        long base = t0 + tl;
        float d = delta[(base << 7) + di];
        float u = xi[(base << 7) + di];
        float Bv = xdbc[base * 36 + DTRK + ds];
        float Cv = xdbc[base * 36 + DTRK + DSN + ds];
        float a = expf(d * Av);
        h = a * h + (d * u) * Bv;
        float yp = h * Cv;
        yp += __shfl_xor(yp, 1);
        yp += __shfl_xor(yp, 2);
        yp += __shfl_xor(yp, 4);
        yp += __shfl_xor(yp, 8);
        if (ds == 0) {
            float y = yp + u * Dv;
            float z = xz[(base << 8) + DIM + di];
            float sig = 1.f / (1.f + expf(-z));
            gated[(base << 7) + di] = y * (z * sig);
        }
    }
}

// ---------------- out_proj GEMM + residual: t[m,c<64] += sum_k gated[m,k<128]*W[c,k] ----------------
__global__ void k_gemm_out(const float* __restrict__ gated, const float* __restrict__ Wo,
                           float* __restrict__ tio) {
    int idx = blockIdx.x * blockDim.x + threadIdx.x;  // MM*64
    int c = idx & 63;
    long m = idx >> 6;
    const float* gr = gated + (m << 7);
    const float* wr = Wo + (c << 7);
    float acc = 0.f;
    for (int k = 0; k < DIM; ++k) acc += gr[k] * wr[k];
    tio[idx] += acc;
}

// ---------------- decoder conv1: reads sequence layout t[b,l,c], writes NCHW ----------------
__global__ void k_dec1_conv(const float* __restrict__ tin, const float* __restrict__ w,
                            const float* __restrict__ bias, float* __restrict__ out) {
    int idx = blockIdx.x * blockDim.x + threadIdx.x;  // (b,co,h,w) 1048576
    int wx = idx & 63;
    int hy = (idx >> 6) & 63;
    int co = (idx >> 12) & 63;
    int b  = idx >> 18;
    float acc = bias[co];
    #pragma unroll
    for (int kh = 0; kh < 3; ++kh) {
        int ih = hy + kh - 1;
        if (ih < 0 || ih >= HH) continue;
        #pragma unroll
        for (int kw = 0; kw < 3; ++kw) {
            int iw = wx + kw - 1;
            if (iw < 0 || iw >= WWD) continue;
            const float* tp = tin + ((((long)b << 12) + (ih << 6) + iw) << 6);
            const float* wp = w + co * 576 + kh * 3 + kw;   // w[co][ci][kh][kw], ci stride 9
            for (int ci = 0; ci < HD; ++ci)
                acc += tp[ci] * wp[ci * 9];
        }
    }
    out[idx] = acc;
}

// ---------------- decoder conv2: (B,64,H,W) NCHW -> (B,10,H,W) ----------------
__global__ void k_dec2_conv(const float* __restrict__ src, const float* __restrict__ w,
                            const float* __restrict__ bias, float* __restrict__ out) {
    int idx = blockIdx.x * blockDim.x + threadIdx.x;  // (b,co,h,w) = 163840
    int wx = idx & 63;
    int hy = (idx >> 6) & 63;
    int t = idx >> 12;
    int co = t % NFC;
    int b = t / NFC;
    float acc = bias[co];
    for (int ci = 0; ci < HD; ++ci) {
        const float* sp = src + ((long)((b << 6) + ci) << 12);
        const float* wp = w + (co * HD + ci) * 9;
        #pragma unroll
        for (int kh = 0; kh < 3; ++kh) {
            int ih = hy + kh - 1;
            if (ih < 0 || ih >= HH) continue;
            #pragma unroll
            for (int kw = 0; kw < 3; ++kw) {
                int iw = wx + kw - 1;
                if (iw < 0 || iw >= WWD) continue;
                acc += sp[(ih << 6) + iw] * wp[kh * 3 + kw];
            }
        }
    }
    out[idx] = acc;
}

extern "C" void kernel_launch(void* const* d_in, const int* in_sizes, int n_in,
                              void* d_out, int out_size, void* d_ws, size_t ws_size,
                              hipStream_t stream) {
    const float* x       = (const float*)d_in[0];
    const float* enc_w   = (const float*)d_in[1];
    const float* enc_b   = (const float*)d_in[2];
    const float* enc_g   = (const float*)d_in[3];
    const float* enc_be  = (const float*)d_in[4];
    const float* in_proj = (const float*)d_in[5];
    const float* conv_w  = (const float*)d_in[6];
    const float* conv_b  = (const float*)d_in[7];
    const float* x_proj  = (const float*)d_in[8];
    const float* dt_w    = (const float*)d_in[9];
    const float* dt_b    = (const float*)d_in[10];
    const float* A_log   = (const float*)d_in[11];
    const float* Dp      = (const float*)d_in[12];
    const float* out_prj = (const float*)d_in[13];
    const float* dec1_w  = (const float*)d_in[14];
    const float* dec1_b  = (const float*)d_in[15];
    const float* dec1_g  = (const float*)d_in[16];
    const float* dec1_be = (const float*)d_in[17];
    const float* dec2_w  = (const float*)d_in[18];
    const float* dec2_b  = (const float*)d_in[19];
    float* out = (float*)d_out;

    // workspace layout (floats); total ~13.96M floats = ~55.9 MB
    float* ws = (float*)d_ws;
    size_t off = 0;
    float* conv_buf  = ws + off; off += 1048576;  // enc/dec conv scratch (B,64,4096)
    float* mv        = ws + off; off += 128;      // mean[64] + var[64]
    float* t_buf     = ws + off; off += 1048576;  // running sequence (B,L,64); reused as dec BN out
    float* xz_buf    = ws + off; off += 4194304;  // (B,L,256)
    float* xi_buf    = ws + off; off += 2097152;  // (B,L,128)
    float* xdbc_buf  = ws + off; off += 589824;   // (B,L,36)
    float* delta_buf = ws + off; off += 2097152;  // (B,L,128)
    float* gated_buf = ws + off; off += 2097152;  // (B,L,128)
    float* Pb        = ws + off; off += 262144;   // (B,DI,DS,NC)
    float* Sb        = ws + off; off += 262144;
    float* hin       = ws + off; off += 262144;
    (void)ws_size; (void)in_sizes; (void)n_in; (void)out_size;

    // encoder
    k_enc_conv<<<4096, 256, 0, stream>>>(x, enc_w, enc_b, conv_buf);
    k_bn_stats<<<64, 256, 0, stream>>>(conv_buf, mv);
    k_bn_apply_seq<<<4096, 256, 0, stream>>>(conv_buf, mv, enc_g, enc_be, t_buf);

    // mamba layers
    dim3 sg(NCHUNK, BB, DIM / 8);
    for (int i = 0; i < NLAYER; ++i) {
        k_gemm_in<<<MM / 8, 256, 0, stream>>>(t_buf, in_proj + (long)i * 2 * DIM * HD, xz_buf);
        k_dwconv_silu<<<MM * DIM / 256, 256, 0, stream>>>(xz_buf, conv_w + i * DIM * DCN,
                                                          conv_b + i * DIM, xi_buf);
        k_gemm_xproj<<<MM * 36 / 256, 256, 0, stream>>>(xi_buf, x_proj + i * 36 * DIM, xdbc_buf);
        k_dt_softplus<<<MM * DIM / 256, 256, 0, stream>>>(xdbc_buf, dt_w + i * DIM * DTRK,
                                                          dt_b + i * DIM, delta_buf);
        k_scan_p1<<<sg, 128, 0, stream>>>(delta_buf, xi_buf, xdbc_buf,
                                          A_log + i * DIM * DSN, Pb, Sb);
        k_scan_p2<<<32, 256, 0, stream>>>(Pb, Sb, hin);
        k_scan_p3<<<sg, 128, 0, stream>>>(delta_buf, xi_buf, xdbc_buf,
                                          A_log + i * DIM * DSN, Dp + i * DIM,
                                          xz_buf, hin, gated_buf);
        k_gemm_out<<<MM * HD / 256, 256, 0, stream>>>(gated_buf, out_prj + i * HD * DIM, t_buf);
    }

    // decoder
    k_dec1_conv<<<4096, 256, 0, stream>>>(t_buf, dec1_w, dec1_b, conv_buf);
    k_bn_stats<<<64, 256, 0, stream>>>(conv_buf, mv);
    float* db_buf = t_buf;  // t no longer needed
    k_bn_apply_nchw<<<4096, 256, 0, stream>>>(conv_buf, mv, dec1_g, dec1_be, db_buf);
    k_dec2_conv<<<640, 256, 0, stream>>>(db_buf, dec2_w, dec2_b, out);
}

// Round 2
// 1172.050 us; speedup vs baseline: 1.4455x; 1.4455x over previous
//
#include <hip/hip_runtime.h>
#include <hip/hip_bf16.h>

// Problem constants (MinimalEventMamba)
#define BB   4
#define NBC  5
#define HD   64
#define NLAYER 4
#define NFC  10
#define DIM  128
#define DSN  16
#define DCN  4
#define DTRK 4
#define HH   64
#define WWD  64
#define LL   4096
#define MM   (BB*LL)
#define NCHUNK 32
#define CLEN   128

// ---------------- Encoder conv: (B,5,64,64) -> (B,64,64,64) NCHW ----------------
__global__ void k_enc_conv(const float* __restrict__ x, const float* __restrict__ w,
                           const float* __restrict__ bias, float* __restrict__ out) {
    int idx = blockIdx.x * blockDim.x + threadIdx.x;
    int wx = idx & 63;
    int hy = (idx >> 6) & 63;
    int co = (idx >> 12) & 63;
    int b  = idx >> 18;
    float acc = bias[co];
    for (int ci = 0; ci < NBC; ++ci) {
        const float* xin = x + (((long)(b * NBC + ci)) << 12);
        const float* wp  = w + (co * NBC + ci) * 9;
        #pragma unroll
        for (int kh = 0; kh < 3; ++kh) {
            int ih = hy + kh - 1;
            if (ih < 0 || ih >= HH) continue;
            #pragma unroll
            for (int kw = 0; kw < 3; ++kw) {
                int iw = wx + kw - 1;
                if (iw < 0 || iw >= WWD) continue;
                acc += xin[(ih << 6) + iw] * wp[kh * 3 + kw];
            }
        }
    }
    out[idx] = acc;
}

// ---------------- BN stats, NCHW layout (encoder path) ----------------
__global__ void k_bn_stats(const float* __restrict__ src, float* __restrict__ mv) {
    __shared__ float s1[256];
    __shared__ float s2[256];
    int c = blockIdx.x;
    int tid = threadIdx.x;
    float sum = 0.f, sq = 0.f;
    for (int i = tid; i < BB * LL; i += 256) {
        int b = i >> 12;
        int hw = i & 4095;
        float v = src[((long)((b << 6) + c) << 12) + hw];
        sum += v; sq += v * v;
    }
    s1[tid] = sum; s2[tid] = sq;
    __syncthreads();
    for (int off = 128; off > 0; off >>= 1) {
        if (tid < off) { s1[tid] += s1[tid + off]; s2[tid] += s2[tid + off]; }
        __syncthreads();
    }
    if (tid == 0) {
        float m = s1[0] * (1.f / 16384.f);
        mv[c] = m;
        mv[64 + c] = s2[0] * (1.f / 16384.f) - m * m;
    }
}

// ---------------- BN+ReLU with LDS transpose: NCHW -> seq [bhw][c] ----------------
__global__ void k_bn_tr_seq(const float* __restrict__ src, const float* __restrict__ mv,
                            const float* __restrict__ g, const float* __restrict__ be,
                            float* __restrict__ tout) {
    __shared__ float s[64 * 65];
    int blk = blockIdx.x;          // b*64 + hwtile
    int b = blk >> 6;
    int hw0 = (blk & 63) << 6;
    int tid = threadIdx.x;
    for (int i = tid; i < 4096; i += 256) {
        int pix = i & 63, c = i >> 6;   // coalesced read along pix
        s[c * 65 + pix] = src[((long)((b << 6) + c) << 12) + hw0 + pix];
    }
    __syncthreads();
    for (int i = tid; i < 4096; i += 256) {
        int c = i & 63, pix = i >> 6;   // coalesced write along c
        float v = s[c * 65 + pix];
        float y = (v - mv[c]) * rsqrtf(mv[64 + c] + 1e-5f) * g[c] + be[c];
        tout[((long)((b << 12) + hw0 + pix) << 6) + c] = fmaxf(y, 0.f);
    }
}

// ---------------- BN+ReLU with LDS transpose: pixel-major [bhw][c] -> NCHW ----------------
__global__ void k_bn_tr_nchw(const float* __restrict__ src, const float* __restrict__ mv,
                             const float* __restrict__ g, const float* __restrict__ be,
                             float* __restrict__ out) {
    __shared__ float s[64 * 65];
    int blk = blockIdx.x;
    int b = blk >> 6;
    int hw0 = (blk & 63) << 6;
    int tid = threadIdx.x;
    for (int i = tid; i < 4096; i += 256) {
        int c = i & 63, pix = i >> 6;   // coalesced read along c
        s[c * 65 + pix] = src[((long)((b << 12) + hw0 + pix) << 6) + c];
    }
    __syncthreads();
    for (int i = tid; i < 4096; i += 256) {
        int pix = i & 63, c = i >> 6;   // coalesced write along pix
        float v = s[c * 65 + pix];
        float y = (v - mv[c]) * rsqrtf(mv[64 + c] + 1e-5f) * g[c] + be[c];
        out[((long)((b << 6) + c) << 12) + hw0 + pix] = fmaxf(y, 0.f);
    }
}

// ---------------- BN stats for pixel-major layout (two stage) ----------------
__global__ void k_bn_stats_pm_part(const float* __restrict__ src, float* __restrict__ pbuf) {
    __shared__ float s1[256], s2[256];
    int g = blockIdx.x;          // 0..63
    int tid = threadIdx.x;
    int c = tid & 63;
    int p = tid >> 6;
    float sum = 0.f, sq = 0.f;
    for (int row = (g << 2) + p; row < MM; row += 256) {
        float v = src[(long)row * 64 + c];   // coalesced (lanes = c)
        sum += v; sq += v * v;
    }
    s1[tid] = sum; s2[tid] = sq;
    __syncthreads();
    if (p == 0) {
        sum = s1[c] + s1[64 + c] + s1[128 + c] + s1[192 + c];
        sq  = s2[c] + s2[64 + c] + s2[128 + c] + s2[192 + c];
        pbuf[(g << 6) + c] = sum;
        pbuf[4096 + (g << 6) + c] = sq;
    }
}

__global__ void k_bn_stats_pm_fin(const float* __restrict__ pbuf, float* __restrict__ mv) {
    int c = threadIdx.x;   // 64 threads
    float s = 0.f, q = 0.f;
    for (int g = 0; g < 64; ++g) {
        s += pbuf[(g << 6) + c];
        q += pbuf[4096 + (g << 6) + c];
    }
    float m = s * (1.f / 16384.f);
    mv[c] = m;
    mv[64 + c] = q * (1.f / 16384.f) - m * m;
}

// ---------------- in_proj GEMM (M=16384,N=256,K=64), LDS tiled ----------------
// grid 512: bx&1 = N-half, bx>>1 = 64-row tile. 256 threads.
__global__ void k_gemm_in_t(const float* __restrict__ tin, const float* __restrict__ Wp,
                            float* __restrict__ xz) {
    __shared__ float ts[64 * 68];
    __shared__ float w_s[128 * 68];
    int bx = blockIdx.x;
    int nh = bx & 1;
    long m0 = (long)(bx >> 1) << 6;
    int tid = threadIdx.x;
    for (int i = tid; i < 4096; i += 256) {
        int r = i >> 6, k = i & 63;
        ts[r * 68 + k] = tin[(m0 << 6) + i];
    }
    const float* wp = Wp + nh * 8192;
    for (int i = tid; i < 8192; i += 256) {
        int n = i >> 6, k = i & 63;
        w_s[n * 68 + k] = wp[i];
    }
    __syncthreads();
    int ncol = tid & 127;
    int rh = (tid >> 7) << 5;       // 0 or 32
    for (int rg = 0; rg < 4; ++rg) {
        int rbase = rh + (rg << 3);
        float acc[8] = {0,0,0,0,0,0,0,0};
        for (int k4 = 0; k4 < 16; ++k4) {
            float4 w4 = *(const float4*)&w_s[ncol * 68 + (k4 << 2)];
            #pragma unroll
            for (int r = 0; r < 8; ++r) {
                float4 a4 = *(const float4*)&ts[(rbase + r) * 68 + (k4 << 2)];
                acc[r] += a4.x * w4.x + a4.y * w4.y + a4.z * w4.z + a4.w * w4.w;
            }
        }
        #pragma unroll
        for (int r = 0; r < 8; ++r)
            xz[(m0 + rbase + r) * 256 + (nh << 7) + ncol] = acc[r];
    }
}

// ---------------- causal depthwise conv (K=4) + SiLU ----------------
__global__ void k_dwconv_silu(const float* __restrict__ xz, const float* __restrict__ cw,
                              const float* __restrict__ cb, float* __restrict__ xi) {
    int idx = blockIdx.x * blockDim.x + threadIdx.x;
    int di = idx & 127;
    int bl = idx >> 7;
    int l = bl & 4095;
    int b = bl >> 12;
    float acc = cb[di];
    #pragma unroll
    for (int k = 0; k < DCN; ++k) {
        int ls = l + k - (DCN - 1);
        if (ls >= 0)
            acc += xz[((((long)b << 12) + ls) << 8) + di] * cw[(di << 2) + k];
    }
    float sig = 1.f / (1.f + expf(-acc));
    xi[idx] = acc * sig;
}

// ---------------- x_proj GEMM (N=36,K=128) + fused dt-proj + softplus ----------------
// grid 512 (32-row tiles), 256 threads.
__global__ void k_xproj_dt_t(const float* __restrict__ xi, const float* __restrict__ Wx,
                             const float* __restrict__ dw, const float* __restrict__ dbias,
                             float* __restrict__ xdbc, float* __restrict__ delta) {
    __shared__ float ts[32 * 132];
    __shared__ float w_s[36 * 132];
    __shared__ float xs[32 * 40];
    long m0 = (long)blockIdx.x << 5;
    int tid = threadIdx.x;
    for (int i = tid; i < 4096; i += 256) {
        int r = i >> 7, k = i & 127;
        ts[r * 132 + k] = xi[(m0 << 7) + i];
    }
    for (int i = tid; i < 4608; i += 256) {
        int n = i >> 7, k = i & 127;
        w_s[n * 132 + k] = Wx[i];
    }
    __syncthreads();
    int n = tid & 63;
    int rg = tid >> 6;
    if (n < 36) {
        float acc[8] = {0,0,0,0,0,0,0,0};
        for (int k4 = 0; k4 < 32; ++k4) {
            float4 w4 = *(const float4*)&w_s[n * 132 + (k4 << 2)];
            #pragma unroll
            for (int r = 0; r < 8; ++r) {
                float4 a4 = *(const float4*)&ts[((rg << 3) + r) * 132 + (k4 << 2)];
                acc[r] += a4.x * w4.x + a4.y * w4.y + a4.z * w4.z + a4.w * w4.w;
            }
        }
        #pragma unroll
        for (int r = 0; r < 8; ++r) {
            int rr = (rg << 3) + r;
            xdbc[(m0 + rr) * 36 + n] = acc[r];
            xs[rr * 40 + n] = acc[r];
        }
    }
    __syncthreads();
    for (int i = tid; i < 4096; i += 256) {
        int r = i >> 7, di = i & 127;
        float v = dbias[di];
        float4 d4 = *(const float4*)&dw[di << 2];
        v += xs[r * 40 + 0] * d4.x + xs[r * 40 + 1] * d4.y
           + xs[r * 40 + 2] * d4.z + xs[r * 40 + 3] * d4.w;
        delta[(m0 + r) * 128 + di] = (v > 20.f) ? v : log1pf(expf(v));
    }
}

// ---------------- selective scan, chunked (3 phases), unchanged ----------------
__global__ void k_scan_p1(const float* __restrict__ delta, const float* __restrict__ xi,
                          const float* __restrict__ xdbc, const float* __restrict__ A_log,
                          float* __restrict__ Pb, float* __restrict__ Sb) {
    int chunk = blockIdx.x;
    int b = blockIdx.y;
    int dg = blockIdx.z;
    int tid = threadIdx.x;
    int dl = tid >> 4;
    int ds = tid & 15;
    int di = (dg << 3) + dl;
    float Av = -expf(A_log[(di << 4) + ds]);
    float h = 0.f, P = 1.f;
    long t0 = (long)b * LL + (long)chunk * CLEN;
    for (int tl = 0; tl < CLEN; ++tl) {
        long base = t0 + tl;
        float d = delta[(base << 7) + di];
        float u = xi[(base << 7) + di];
        float Bv = xdbc[base * 36 + DTRK + ds];
        float a = expf(d * Av);
        h = a * h + (d * u) * Bv;
        P *= a;
    }
    long sidx = ((((long)b * DIM + di) << 4) + ds) * NCHUNK + chunk;
    Pb[sidx] = P;
    Sb[sidx] = h;
}

__global__ void k_scan_p2(const float* __restrict__ Pb, const float* __restrict__ Sb,
                          float* __restrict__ hin) {
    int s = blockIdx.x * blockDim.x + threadIdx.x;
    long base = (long)s * NCHUNK;
    float h = 0.f;
    for (int c = 0; c < NCHUNK; ++c) {
        hin[base + c] = h;
        h = Pb[base + c] * h + Sb[base + c];
    }
}

__global__ void k_scan_p3(const float* __restrict__ delta, const float* __restrict__ xi,
                          const float* __restrict__ xdbc, const float* __restrict__ A_log,
                          const float* __restrict__ Dp, const float* __restrict__ xz,
                          const float* __restrict__ hin, float* __restrict__ gated) {
    int chunk = blockIdx.x;
    int b = blockIdx.y;
    int dg = blockIdx.z;
    int tid = threadIdx.x;
    int dl = tid >> 4;
    int ds = tid & 15;
    int di = (dg << 3) + dl;
    float Av = -expf(A_log[(di << 4) + ds]);
    float Dv = Dp[di];
    float h = hin[((((long)b * DIM + di) << 4) + ds) * NCHUNK + chunk];
    long t0 = (long)b * LL + (long)chunk * CLEN;
    for (int tl = 0; tl < CLEN; ++tl) {
        long base = t0 + tl;
        float d = delta[(base << 7) + di];
        float u = xi[(base << 7) + di];
        float Bv = xdbc[base * 36 + DTRK + ds];
        float Cv = xdbc[base * 36 + DTRK + DSN + ds];
        float a = expf(d * Av);
        h = a * h + (d * u) * Bv;
        float yp = h * Cv;
        yp += __shfl_xor(yp, 1);
        yp += __shfl_xor(yp, 2);
        yp += __shfl_xor(yp, 4);
        yp += __shfl_xor(yp, 8);
        if (ds == 0) {
            float y = yp + u * Dv;
            float z = xz[(base << 8) + DIM + di];
            float sig = 1.f / (1.f + expf(-z));
            gated[(base << 7) + di] = y * (z * sig);
        }
    }
}

// ---------------- out_proj GEMM (N=64,K=128) + residual, LDS tiled ----------------
__global__ void k_gemm_out_t(const float* __restrict__ gated, const float* __restrict__ Wo,
                             float* __restrict__ tio) {
    __shared__ float ts[32 * 132];
    __shared__ float w_s[64 * 132];
    long m0 = (long)blockIdx.x << 5;
    int tid = threadIdx.x;
    for (int i = tid; i < 4096; i += 256) {
        int r = i >> 7, k = i & 127;
        ts[r * 132 + k] = gated[(m0 << 7) + i];
    }
    for (int i = tid; i < 8192; i += 256) {
        int nn = i >> 7, k = i & 127;
        w_s[nn * 132 + k] = Wo[i];
    }
    __syncthreads();
    int n = tid & 63;
    int rg = tid >> 6;
    float acc[8] = {0,0,0,0,0,0,0,0};
    for (int k4 = 0; k4 < 32; ++k4) {
        float4 w4 = *(const float4*)&w_s[n * 132 + (k4 << 2)];
        #pragma unroll
        for (int r = 0; r < 8; ++r) {
            float4 a4 = *(const float4*)&ts[((rg << 3) + r) * 132 + (k4 << 2)];
            acc[r] += a4.x * w4.x + a4.y * w4.y + a4.z * w4.z + a4.w * w4.w;
        }
    }
    #pragma unroll
    for (int r = 0; r < 8; ++r) {
        long m = m0 + (rg << 3) + r;
        tio[m * 64 + n] += acc[r];
    }
}

// ---------------- dec1 weight transpose: [co][ci][tap] -> [tap][ci][co] ----------------
__global__ void k_prep_wdec1(const float* __restrict__ w, float* __restrict__ wT) {
    int idx = blockIdx.x * blockDim.x + threadIdx.x;   // 36864
    int co = idx & 63;
    int ci = (idx >> 6) & 63;
    int tap = idx >> 12;
    wT[idx] = w[co * 576 + ci * 9 + tap];
}

// ---------------- decoder conv1, LDS tiled: seq [bhw][c] in -> pixel-major [bhw][co] out ----------------
// grid (64 tiles, B), 256 threads; thread = 4 px x 4 co.
__global__ void k_dec1_conv_t(const float* __restrict__ tin, const float* __restrict__ wT,
                              const float* __restrict__ bias, float* __restrict__ out) {
    __shared__ float x_s[64 * 101];      // [ci][100 px], stride 101 (conflict-free)
    __shared__ float w_s[64 * 64];       // [ci][co] for current tap
    int tile = blockIdx.x;
    int b = blockIdx.y;
    int ty0 = (tile >> 3) << 3;
    int tx0 = (tile & 7) << 3;
    int tid = threadIdx.x;

    for (int i = tid; i < 6400; i += 256) {
        int pl = i >> 6;         // 0..99
        int c = i & 63;          // coalesced along c
        int py = pl / 10, px = pl - py * 10;
        int ih = ty0 + py - 1, iw = tx0 + px - 1;
        float v = 0.f;
        if (ih >= 0 && ih < HH && iw >= 0 && iw < WWD)
            v = tin[((long)((b << 12) + (ih << 6) + iw)) * 64 + c];
        x_s[c * 101 + pl] = v;
    }

    int p4 = tid & 15;
    int c4 = tid >> 4;
    int py = p4 >> 1;
    int px2 = (p4 & 1) << 2;
    float acc[4][4];
    #pragma unroll
    for (int j = 0; j < 4; ++j)
        #pragma unroll
        for (int co = 0; co < 4; ++co) acc[j][co] = 0.f;

    for (int tap = 0; tap < 9; ++tap) {
        __syncthreads();
        for (int i = tid; i < 4096; i += 256)
            w_s[i] = wT[tap * 4096 + i];
        __syncthreads();
        int kh = tap / 3, kw = tap - kh * 3;
        int xbase = (py + kh) * 10 + px2 + kw;
        for (int ci = 0; ci < 64; ++ci) {
            float4 w4 = *(const float4*)&w_s[(ci << 6) + (c4 << 2)];
            const float* xr = &x_s[ci * 101 + xbase];
            #pragma unroll
            for (int j = 0; j < 4; ++j) {
                float xv = xr[j];
                acc[j][0] += xv * w4.x;
                acc[j][1] += xv * w4.y;
                acc[j][2] += xv * w4.z;
                acc[j][3] += xv * w4.w;
            }
        }
    }
    float4 bv = *(const float4*)&bias[c4 << 2];
    #pragma unroll
    for (int j = 0; j < 4; ++j) {
        int hw = ((ty0 + py) << 6) + tx0 + px2 + j;
        float4 o;
        o.x = acc[j][0] + bv.x; o.y = acc[j][1] + bv.y;
        o.z = acc[j][2] + bv.z; o.w = acc[j][3] + bv.w;
        *(float4*)&out[((long)((b << 12) + hw)) * 64 + (c4 << 2)] = o;
    }
}

// ---------------- decoder conv2: NCHW (B,64,H,W) -> (B,10,H,W) ----------------
__global__ void k_dec2_conv(const float* __restrict__ src, const float* __restrict__ w,
                            const float* __restrict__ bias, float* __restrict__ out) {
    int idx = blockIdx.x * blockDim.x + threadIdx.x;
    int wx = idx & 63;
    int hy = (idx >> 6) & 63;
    int t = idx >> 12;
    int co = t % NFC;
    int b = t / NFC;
    float acc = bias[co];
    for (int ci = 0; ci < HD; ++ci) {
        const float* sp = src + ((long)((b << 6) + ci) << 12);
        const float* wp = w + (co * HD + ci) * 9;
        #pragma unroll
        for (int kh = 0; kh < 3; ++kh) {
            int ih = hy + kh - 1;
            if (ih < 0 || ih >= HH) continue;
            #pragma unroll
            for (int kw = 0; kw < 3; ++kw) {
                int iw = wx + kw - 1;
                if (iw < 0 || iw >= WWD) continue;
                acc += sp[(ih << 6) + iw] * wp[kh * 3 + kw];
            }
        }
    }
    out[idx] = acc;
}

extern "C" void kernel_launch(void* const* d_in, const int* in_sizes, int n_in,
                              void* d_out, int out_size, void* d_ws, size_t ws_size,
                              hipStream_t stream) {
    const float* x       = (const float*)d_in[0];
    const float* enc_w   = (const float*)d_in[1];
    const float* enc_b   = (const float*)d_in[2];
    const float* enc_g   = (const float*)d_in[3];
    const float* enc_be  = (const float*)d_in[4];
    const float* in_proj = (const float*)d_in[5];
    const float* conv_w  = (const float*)d_in[6];
    const float* conv_b  = (const float*)d_in[7];
    const float* x_proj  = (const float*)d_in[8];
    const float* dt_w    = (const float*)d_in[9];
    const float* dt_b    = (const float*)d_in[10];
    const float* A_log   = (const float*)d_in[11];
    const float* Dp      = (const float*)d_in[12];
    const float* out_prj = (const float*)d_in[13];
    const float* dec1_w  = (const float*)d_in[14];
    const float* dec1_b  = (const float*)d_in[15];
    const float* dec1_g  = (const float*)d_in[16];
    const float* dec1_be = (const float*)d_in[17];
    const float* dec2_w  = (const float*)d_in[18];
    const float* dec2_b  = (const float*)d_in[19];
    float* out = (float*)d_out;

    float* ws = (float*)d_ws;
    size_t off = 0;
    float* conv_buf  = ws + off; off += 1048576;  // enc NCHW / dec1 pixel-major scratch
    float* mv        = ws + off; off += 128;
    float* pbuf      = ws + off; off += 8192;
    float* wT1       = ws + off; off += 36864;
    float* t_buf     = ws + off; off += 1048576;
    float* xz_buf    = ws + off; off += 4194304;
    float* xi_buf    = ws + off; off += 2097152;
    float* xdbc_buf  = ws + off; off += 589824;
    float* delta_buf = ws + off; off += 2097152;
    float* gated_buf = ws + off; off += 2097152;
    float* Pb        = ws + off; off += 262144;
    float* Sb        = ws + off; off += 262144;
    float* hin       = ws + off; off += 262144;
    (void)ws_size; (void)in_sizes; (void)n_in; (void)out_size;

    // encoder
    k_enc_conv<<<4096, 256, 0, stream>>>(x, enc_w, enc_b, conv_buf);
    k_bn_stats<<<64, 256, 0, stream>>>(conv_buf, mv);
    k_bn_tr_seq<<<256, 256, 0, stream>>>(conv_buf, mv, enc_g, enc_be, t_buf);

    // mamba layers
    dim3 sg(NCHUNK, BB, DIM / 8);
    for (int i = 0; i < NLAYER; ++i) {
        k_gemm_in_t<<<512, 256, 0, stream>>>(t_buf, in_proj + (long)i * 2 * DIM * HD, xz_buf);
        k_dwconv_silu<<<MM * DIM / 256, 256, 0, stream>>>(xz_buf, conv_w + i * DIM * DCN,
                                                          conv_b + i * DIM, xi_buf);
        k_xproj_dt_t<<<512, 256, 0, stream>>>(xi_buf, x_proj + i * 36 * DIM,
                                              dt_w + i * DIM * DTRK, dt_b + i * DIM,
                                              xdbc_buf, delta_buf);
        k_scan_p1<<<sg, 128, 0, stream>>>(delta_buf, xi_buf, xdbc_buf,
                                          A_log + i * DIM * DSN, Pb, Sb);
        k_scan_p2<<<32, 256, 0, stream>>>(Pb, Sb, hin);
        k_scan_p3<<<sg, 128, 0, stream>>>(delta_buf, xi_buf, xdbc_buf,
                                          A_log + i * DIM * DSN, Dp + i * DIM,
                                          xz_buf, hin, gated_buf);
        k_gemm_out_t<<<512, 256, 0, stream>>>(gated_buf, out_prj + i * HD * DIM, t_buf);
    }

    // decoder
    k_prep_wdec1<<<144, 256, 0, stream>>>(dec1_w, wT1);
    dim3 dg1(64, BB);
    k_dec1_conv_t<<<dg1, 256, 0, stream>>>(t_buf, wT1, dec1_b, conv_buf);
    k_bn_stats_pm_part<<<64, 256, 0, stream>>>(conv_buf, pbuf);
    k_bn_stats_pm_fin<<<1, 64, 0, stream>>>(pbuf, mv);
    float* db_buf = t_buf;  // reuse: t no longer needed
    k_bn_tr_nchw<<<256, 256, 0, stream>>>(conv_buf, mv, dec1_g, dec1_be, db_buf);
    k_dec2_conv<<<640, 256, 0, stream>>>(db_buf, dec2_w, dec2_b, out);
}

// Round 3
// 764.337 us; speedup vs baseline: 2.2166x; 1.5334x over previous
//
#include <hip/hip_runtime.h>
#include <hip/hip_bf16.h>

// Problem constants (MinimalEventMamba)
#define BB   4
#define NBC  5
#define HD   64
#define NLAYER 4
#define NFC  10
#define DIM  128
#define DSN  16
#define DCN  4
#define DTRK 4
#define HH   64
#define WWD  64
#define LL   4096
#define MM   (BB*LL)
#define NCHUNK 128
#define CLEN   32      // NCHUNK*CLEN == LL
#define TSTEP  16      // LDS staging tile (CLEN % TSTEP == 0)

// ---------------- Encoder conv: (B,5,64,64) -> (B,64,64,64) NCHW ----------------
__global__ void k_enc_conv(const float* __restrict__ x, const float* __restrict__ w,
                           const float* __restrict__ bias, float* __restrict__ out) {
    int idx = blockIdx.x * blockDim.x + threadIdx.x;
    int wx = idx & 63;
    int hy = (idx >> 6) & 63;
    int co = (idx >> 12) & 63;
    int b  = idx >> 18;
    float acc = bias[co];
    for (int ci = 0; ci < NBC; ++ci) {
        const float* xin = x + (((long)(b * NBC + ci)) << 12);
        const float* wp  = w + (co * NBC + ci) * 9;
        #pragma unroll
        for (int kh = 0; kh < 3; ++kh) {
            int ih = hy + kh - 1;
            if (ih < 0 || ih >= HH) continue;
            #pragma unroll
            for (int kw = 0; kw < 3; ++kw) {
                int iw = wx + kw - 1;
                if (iw < 0 || iw >= WWD) continue;
                acc += xin[(ih << 6) + iw] * wp[kh * 3 + kw];
            }
        }
    }
    out[idx] = acc;
}

// ---------------- BN stats, NCHW layout (encoder path) ----------------
__global__ void k_bn_stats(const float* __restrict__ src, float* __restrict__ mv) {
    __shared__ float s1[256];
    __shared__ float s2[256];
    int c = blockIdx.x;
    int tid = threadIdx.x;
    float sum = 0.f, sq = 0.f;
    for (int i = tid; i < BB * LL; i += 256) {
        int b = i >> 12;
        int hw = i & 4095;
        float v = src[((long)((b << 6) + c) << 12) + hw];
        sum += v; sq += v * v;
    }
    s1[tid] = sum; s2[tid] = sq;
    __syncthreads();
    for (int off = 128; off > 0; off >>= 1) {
        if (tid < off) { s1[tid] += s1[tid + off]; s2[tid] += s2[tid + off]; }
        __syncthreads();
    }
    if (tid == 0) {
        float m = s1[0] * (1.f / 16384.f);
        mv[c] = m;
        mv[64 + c] = s2[0] * (1.f / 16384.f) - m * m;
    }
}

// ---------------- BN+ReLU with LDS transpose: NCHW -> seq [bhw][c] ----------------
__global__ void k_bn_tr_seq(const float* __restrict__ src, const float* __restrict__ mv,
                            const float* __restrict__ g, const float* __restrict__ be,
                            float* __restrict__ tout) {
    __shared__ float s[64 * 65];
    int blk = blockIdx.x;
    int b = blk >> 6;
    int hw0 = (blk & 63) << 6;
    int tid = threadIdx.x;
    for (int i = tid; i < 4096; i += 256) {
        int pix = i & 63, c = i >> 6;
        s[c * 65 + pix] = src[((long)((b << 6) + c) << 12) + hw0 + pix];
    }
    __syncthreads();
    for (int i = tid; i < 4096; i += 256) {
        int c = i & 63, pix = i >> 6;
        float v = s[c * 65 + pix];
        float y = (v - mv[c]) * rsqrtf(mv[64 + c] + 1e-5f) * g[c] + be[c];
        tout[((long)((b << 12) + hw0 + pix) << 6) + c] = fmaxf(y, 0.f);
    }
}

// ---------------- BN+ReLU with LDS transpose: pixel-major [bhw][c] -> NCHW ----------------
__global__ void k_bn_tr_nchw(const float* __restrict__ src, const float* __restrict__ mv,
                             const float* __restrict__ g, const float* __restrict__ be,
                             float* __restrict__ out) {
    __shared__ float s[64 * 65];
    int blk = blockIdx.x;
    int b = blk >> 6;
    int hw0 = (blk & 63) << 6;
    int tid = threadIdx.x;
    for (int i = tid; i < 4096; i += 256) {
        int c = i & 63, pix = i >> 6;
        s[c * 65 + pix] = src[((long)((b << 12) + hw0 + pix) << 6) + c];
    }
    __syncthreads();
    for (int i = tid; i < 4096; i += 256) {
        int pix = i & 63, c = i >> 6;
        float v = s[c * 65 + pix];
        float y = (v - mv[c]) * rsqrtf(mv[64 + c] + 1e-5f) * g[c] + be[c];
        out[((long)((b << 6) + c) << 12) + hw0 + pix] = fmaxf(y, 0.f);
    }
}

// ---------------- BN stats for pixel-major layout (two stage) ----------------
__global__ void k_bn_stats_pm_part(const float* __restrict__ src, float* __restrict__ pbuf) {
    __shared__ float s1[256], s2[256];
    int g = blockIdx.x;
    int tid = threadIdx.x;
    int c = tid & 63;
    int p = tid >> 6;
    float sum = 0.f, sq = 0.f;
    for (int row = (g << 2) + p; row < MM; row += 256) {
        float v = src[(long)row * 64 + c];
        sum += v; sq += v * v;
    }
    s1[tid] = sum; s2[tid] = sq;
    __syncthreads();
    if (p == 0) {
        sum = s1[c] + s1[64 + c] + s1[128 + c] + s1[192 + c];
        sq  = s2[c] + s2[64 + c] + s2[128 + c] + s2[192 + c];
        pbuf[(g << 6) + c] = sum;
        pbuf[4096 + (g << 6) + c] = sq;
    }
}

__global__ void k_bn_stats_pm_fin(const float* __restrict__ pbuf, float* __restrict__ mv) {
    int c = threadIdx.x;
    float s = 0.f, q = 0.f;
    for (int g = 0; g < 64; ++g) {
        s += pbuf[(g << 6) + c];
        q += pbuf[4096 + (g << 6) + c];
    }
    float m = s * (1.f / 16384.f);
    mv[c] = m;
    mv[64 + c] = q * (1.f / 16384.f) - m * m;
}

// ---------------- in_proj GEMM (M=16384,N=256,K=64), LDS tiled ----------------
__global__ void k_gemm_in_t(const float* __restrict__ tin, const float* __restrict__ Wp,
                            float* __restrict__ xz) {
    __shared__ float ts[64 * 68];
    __shared__ float w_s[128 * 68];
    int bx = blockIdx.x;
    int nh = bx & 1;
    long m0 = (long)(bx >> 1) << 6;
    int tid = threadIdx.x;
    for (int i = tid; i < 4096; i += 256) {
        int r = i >> 6, k = i & 63;
        ts[r * 68 + k] = tin[(m0 << 6) + i];
    }
    const float* wp = Wp + nh * 8192;
    for (int i = tid; i < 8192; i += 256) {
        int n = i >> 6, k = i & 63;
        w_s[n * 68 + k] = wp[i];
    }
    __syncthreads();
    int ncol = tid & 127;
    int rh = (tid >> 7) << 5;
    for (int rg = 0; rg < 4; ++rg) {
        int rbase = rh + (rg << 3);
        float acc[8] = {0,0,0,0,0,0,0,0};
        for (int k4 = 0; k4 < 16; ++k4) {
            float4 w4 = *(const float4*)&w_s[ncol * 68 + (k4 << 2)];
            #pragma unroll
            for (int r = 0; r < 8; ++r) {
                float4 a4 = *(const float4*)&ts[(rbase + r) * 68 + (k4 << 2)];
                acc[r] += a4.x * w4.x + a4.y * w4.y + a4.z * w4.z + a4.w * w4.w;
            }
        }
        #pragma unroll
        for (int r = 0; r < 8; ++r)
            xz[(m0 + rbase + r) * 256 + (nh << 7) + ncol] = acc[r];
    }
}

// ---------------- causal depthwise conv (K=4) + SiLU ----------------
__global__ void k_dwconv_silu(const float* __restrict__ xz, const float* __restrict__ cw,
                              const float* __restrict__ cb, float* __restrict__ xi) {
    int idx = blockIdx.x * blockDim.x + threadIdx.x;
    int di = idx & 127;
    int bl = idx >> 7;
    int l = bl & 4095;
    int b = bl >> 12;
    float acc = cb[di];
    #pragma unroll
    for (int k = 0; k < DCN; ++k) {
        int ls = l + k - (DCN - 1);
        if (ls >= 0)
            acc += xz[((((long)b << 12) + ls) << 8) + di] * cw[(di << 2) + k];
    }
    float sig = 1.f / (1.f + expf(-acc));
    xi[idx] = acc * sig;
}

// ---------------- x_proj GEMM (N=36,K=128) + fused dt-proj + softplus ----------------
__global__ void k_xproj_dt_t(const float* __restrict__ xi, const float* __restrict__ Wx,
                             const float* __restrict__ dw, const float* __restrict__ dbias,
                             float* __restrict__ xdbc, float* __restrict__ delta) {
    __shared__ float ts[32 * 132];
    __shared__ float w_s[36 * 132];
    __shared__ float xs[32 * 40];
    long m0 = (long)blockIdx.x << 5;
    int tid = threadIdx.x;
    for (int i = tid; i < 4096; i += 256) {
        int r = i >> 7, k = i & 127;
        ts[r * 132 + k] = xi[(m0 << 7) + i];
    }
    for (int i = tid; i < 4608; i += 256) {
        int n = i >> 7, k = i & 127;
        w_s[n * 132 + k] = Wx[i];
    }
    __syncthreads();
    int n = tid & 63;
    int rg = tid >> 6;
    if (n < 36) {
        float acc[8] = {0,0,0,0,0,0,0,0};
        for (int k4 = 0; k4 < 32; ++k4) {
            float4 w4 = *(const float4*)&w_s[n * 132 + (k4 << 2)];
            #pragma unroll
            for (int r = 0; r < 8; ++r) {
                float4 a4 = *(const float4*)&ts[((rg << 3) + r) * 132 + (k4 << 2)];
                acc[r] += a4.x * w4.x + a4.y * w4.y + a4.z * w4.z + a4.w * w4.w;
            }
        }
        #pragma unroll
        for (int r = 0; r < 8; ++r) {
            int rr = (rg << 3) + r;
            xdbc[(m0 + rr) * 36 + n] = acc[r];
            xs[rr * 40 + n] = acc[r];
        }
    }
    __syncthreads();
    for (int i = tid; i < 4096; i += 256) {
        int r = i >> 7, di = i & 127;
        float v = dbias[di];
        float4 d4 = *(const float4*)&dw[di << 2];
        v += xs[r * 40 + 0] * d4.x + xs[r * 40 + 1] * d4.y
           + xs[r * 40 + 2] * d4.z + xs[r * 40 + 3] * d4.w;
        delta[(m0 + r) * 128 + di] = (v > 20.f) ? v : log1pf(expf(v));
    }
}

// ---------------- selective scan, chunked, 4 ds-states per thread ----------------
// Thread map: dq = tid&3 (ds quarter), dil = tid>>2 (0..63); di = half*64+dil.
// P/S layout: [chunk][b][di*16+ds]  (2048 states per (chunk,b)) -> coalesced everywhere.

__global__ void k_scan_p1(const float* __restrict__ delta, const float* __restrict__ xi,
                          const float* __restrict__ xdbc, const float* __restrict__ A_log,
                          float* __restrict__ Pb, float* __restrict__ Sb) {
    __shared__ float d_s[TSTEP][64];
    __shared__ float u_s[TSTEP][64];
    __shared__ float b_s[TSTEP][16];
    int chunk = blockIdx.x, b = blockIdx.y, half = blockIdx.z;
    int tid = threadIdx.x;
    int dq = tid & 3;
    int dil = tid >> 2;
    int di = (half << 6) + dil;
    float4 al = *(const float4*)&A_log[(di << 4) + (dq << 2)];
    float Av[4] = { -expf(al.x), -expf(al.y), -expf(al.z), -expf(al.w) };
    float h[4] = {0.f, 0.f, 0.f, 0.f};
    float P[4] = {1.f, 1.f, 1.f, 1.f};
    long t0 = ((long)b << 12) + (long)chunk * CLEN;

    int srow = tid >> 4, sc4 = (tid & 15) << 2;
    for (int tile = 0; tile < CLEN / TSTEP; ++tile) {
        __syncthreads();
        long ls = t0 + tile * TSTEP + srow;
        *(float4*)&d_s[srow][sc4] = *(const float4*)&delta[(ls << 7) + (half << 6) + sc4];
        *(float4*)&u_s[srow][sc4] = *(const float4*)&xi[(ls << 7) + (half << 6) + sc4];
        if (tid < 64) {
            int r2 = tid >> 2, cc = (tid & 3) << 2;
            long l2 = t0 + tile * TSTEP + r2;
            *(float4*)&b_s[r2][cc] = *(const float4*)&xdbc[l2 * 36 + DTRK + cc];
        }
        __syncthreads();
        #pragma unroll
        for (int i = 0; i < TSTEP; ++i) {
            float d = d_s[i][dil];
            float u = u_s[i][dil];
            float du = d * u;
            float4 Bv = *(float4*)&b_s[i][dq << 2];
            float a0 = __expf(d * Av[0]); h[0] = a0 * h[0] + du * Bv.x; P[0] *= a0;
            float a1 = __expf(d * Av[1]); h[1] = a1 * h[1] + du * Bv.y; P[1] *= a1;
            float a2 = __expf(d * Av[2]); h[2] = a2 * h[2] + du * Bv.z; P[2] *= a2;
            float a3 = __expf(d * Av[3]); h[3] = a3 * h[3] + du * Bv.w; P[3] *= a3;
        }
    }
    long o = (((long)chunk * BB + b) << 11) + (di << 4) + (dq << 2);
    *(float4*)&Pb[o] = make_float4(P[0], P[1], P[2], P[3]);
    *(float4*)&Sb[o] = make_float4(h[0], h[1], h[2], h[3]);
}

// phase2: stitch chunks; writes chunk-entry state IN PLACE into Pb (hin == Pb).
__global__ void k_scan_p2(float* Pb, const float* __restrict__ Sb) {
    int t = blockIdx.x * blockDim.x + threadIdx.x;   // 8192
    int b = t >> 11;
    int s = t & 2047;
    float h = 0.f;
    for (int c = 0; c < NCHUNK; ++c) {
        long idx = (((long)c * BB + b) << 11) + s;
        float p = Pb[idx];
        float sv = Sb[idx];
        Pb[idx] = h;                 // entry state for chunk c
        h = p * h + sv;
    }
}

__global__ void k_scan_p3(const float* __restrict__ delta, const float* __restrict__ xi,
                          const float* __restrict__ xdbc, const float* __restrict__ A_log,
                          const float* __restrict__ Dp, const float* __restrict__ xz,
                          const float* __restrict__ hin, float* __restrict__ gated) {
    __shared__ float d_s[TSTEP][64];
    __shared__ float u_s[TSTEP][64];
    __shared__ float bc_s[TSTEP][32];
    __shared__ float y_s[TSTEP][64];
    int chunk = blockIdx.x, b = blockIdx.y, half = blockIdx.z;
    int tid = threadIdx.x;
    int dq = tid & 3;
    int dil = tid >> 2;
    int di = (half << 6) + dil;
    float4 al = *(const float4*)&A_log[(di << 4) + (dq << 2)];
    float Av[4] = { -expf(al.x), -expf(al.y), -expf(al.z), -expf(al.w) };
    float Dv = Dp[di];
    long ho = (((long)chunk * BB + b) << 11) + (di << 4) + (dq << 2);
    float4 h4 = *(const float4*)&hin[ho];
    float h[4] = { h4.x, h4.y, h4.z, h4.w };
    long t0 = ((long)b << 12) + (long)chunk * CLEN;

    int srow = tid >> 4, sc4 = (tid & 15) << 2;
    for (int tile = 0; tile < CLEN / TSTEP; ++tile) {
        __syncthreads();
        long ls = t0 + tile * TSTEP + srow;
        *(float4*)&d_s[srow][sc4] = *(const float4*)&delta[(ls << 7) + (half << 6) + sc4];
        *(float4*)&u_s[srow][sc4] = *(const float4*)&xi[(ls << 7) + (half << 6) + sc4];
        if (tid < 128) {
            int r2 = tid >> 3, cc = (tid & 7) << 2;
            long l2 = t0 + tile * TSTEP + r2;
            *(float4*)&bc_s[r2][cc] = *(const float4*)&xdbc[l2 * 36 + DTRK + cc];
        }
        __syncthreads();
        #pragma unroll
        for (int i = 0; i < TSTEP; ++i) {
            float d = d_s[i][dil];
            float u = u_s[i][dil];
            float du = d * u;
            float4 Bv = *(float4*)&bc_s[i][dq << 2];
            float4 Cv = *(float4*)&bc_s[i][16 + (dq << 2)];
            float a0 = __expf(d * Av[0]); h[0] = a0 * h[0] + du * Bv.x;
            float a1 = __expf(d * Av[1]); h[1] = a1 * h[1] + du * Bv.y;
            float a2 = __expf(d * Av[2]); h[2] = a2 * h[2] + du * Bv.z;
            float a3 = __expf(d * Av[3]); h[3] = a3 * h[3] + du * Bv.w;
            float yp = h[0] * Cv.x + h[1] * Cv.y + h[2] * Cv.z + h[3] * Cv.w;
            yp += __shfl_xor(yp, 1);
            yp += __shfl_xor(yp, 2);
            if (dq == 0)
                y_s[i][dil] = yp + u * Dv;
        }
        __syncthreads();
        // gated store: y * silu(z), coalesced
        {
            long l = t0 + tile * TSTEP + srow;
            float4 y4 = *(float4*)&y_s[srow][sc4];
            float4 z4 = *(const float4*)&xz[(l << 8) + DIM + (half << 6) + sc4];
            float4 o;
            o.x = y4.x * (z4.x / (1.f + __expf(-z4.x)));
            o.y = y4.y * (z4.y / (1.f + __expf(-z4.y)));
            o.z = y4.z * (z4.z / (1.f + __expf(-z4.z)));
            o.w = y4.w * (z4.w / (1.f + __expf(-z4.w)));
            *(float4*)&gated[(l << 7) + (half << 6) + sc4] = o;
        }
    }
}

// ---------------- out_proj GEMM (N=64,K=128) + residual, LDS tiled ----------------
__global__ void k_gemm_out_t(const float* __restrict__ gated, const float* __restrict__ Wo,
                             float* __restrict__ tio) {
    __shared__ float ts[32 * 132];
    __shared__ float w_s[64 * 132];
    long m0 = (long)blockIdx.x << 5;
    int tid = threadIdx.x;
    for (int i = tid; i < 4096; i += 256) {
        int r = i >> 7, k = i & 127;
        ts[r * 132 + k] = gated[(m0 << 7) + i];
    }
    for (int i = tid; i < 8192; i += 256) {
        int nn = i >> 7, k = i & 127;
        w_s[nn * 132 + k] = Wo[i];
    }
    __syncthreads();
    int n = tid & 63;
    int rg = tid >> 6;
    float acc[8] = {0,0,0,0,0,0,0,0};
    for (int k4 = 0; k4 < 32; ++k4) {
        float4 w4 = *(const float4*)&w_s[n * 132 + (k4 << 2)];
        #pragma unroll
        for (int r = 0; r < 8; ++r) {
            float4 a4 = *(const float4*)&ts[((rg << 3) + r) * 132 + (k4 << 2)];
            acc[r] += a4.x * w4.x + a4.y * w4.y + a4.z * w4.z + a4.w * w4.w;
        }
    }
    #pragma unroll
    for (int r = 0; r < 8; ++r) {
        long m = m0 + (rg << 3) + r;
        tio[m * 64 + n] += acc[r];
    }
}

// ---------------- dec1 weight transpose: [co][ci][tap] -> [tap][ci][co] ----------------
__global__ void k_prep_wdec1(const float* __restrict__ w, float* __restrict__ wT) {
    int idx = blockIdx.x * blockDim.x + threadIdx.x;
    int co = idx & 63;
    int ci = (idx >> 6) & 63;
    int tap = idx >> 12;
    wT[idx] = w[co * 576 + ci * 9 + tap];
}

// ---------------- decoder conv1, LDS tiled ----------------
__global__ void k_dec1_conv_t(const float* __restrict__ tin, const float* __restrict__ wT,
                              const float* __restrict__ bias, float* __restrict__ out) {
    __shared__ float x_s[64 * 101];
    __shared__ float w_s[64 * 64];
    int tile = blockIdx.x;
    int b = blockIdx.y;
    int ty0 = (tile >> 3) << 3;
    int tx0 = (tile & 7) << 3;
    int tid = threadIdx.x;

    for (int i = tid; i < 6400; i += 256) {
        int pl = i >> 6;
        int c = i & 63;
        int py = pl / 10, px = pl - py * 10;
        int ih = ty0 + py - 1, iw = tx0 + px - 1;
        float v = 0.f;
        if (ih >= 0 && ih < HH && iw >= 0 && iw < WWD)
            v = tin[((long)((b << 12) + (ih << 6) + iw)) * 64 + c];
        x_s[c * 101 + pl] = v;
    }

    int p4 = tid & 15;
    int c4 = tid >> 4;
    int py = p4 >> 1;
    int px2 = (p4 & 1) << 2;
    float acc[4][4];
    #pragma unroll
    for (int j = 0; j < 4; ++j)
        #pragma unroll
        for (int co = 0; co < 4; ++co) acc[j][co] = 0.f;

    for (int tap = 0; tap < 9; ++tap) {
        __syncthreads();
        for (int i = tid; i < 4096; i += 256)
            w_s[i] = wT[tap * 4096 + i];
        __syncthreads();
        int kh = tap / 3, kw = tap - kh * 3;
        int xbase = (py + kh) * 10 + px2 + kw;
        for (int ci = 0; ci < 64; ++ci) {
            float4 w4 = *(const float4*)&w_s[(ci << 6) + (c4 << 2)];
            const float* xr = &x_s[ci * 101 + xbase];
            #pragma unroll
            for (int j = 0; j < 4; ++j) {
                float xv = xr[j];
                acc[j][0] += xv * w4.x;
                acc[j][1] += xv * w4.y;
                acc[j][2] += xv * w4.z;
                acc[j][3] += xv * w4.w;
            }
        }
    }
    float4 bv = *(const float4*)&bias[c4 << 2];
    #pragma unroll
    for (int j = 0; j < 4; ++j) {
        int hw = ((ty0 + py) << 6) + tx0 + px2 + j;
        float4 o;
        o.x = acc[j][0] + bv.x; o.y = acc[j][1] + bv.y;
        o.z = acc[j][2] + bv.z; o.w = acc[j][3] + bv.w;
        *(float4*)&out[((long)((b << 12) + hw)) * 64 + (c4 << 2)] = o;
    }
}

// ---------------- decoder conv2: NCHW (B,64,H,W) -> (B,10,H,W) ----------------
__global__ void k_dec2_conv(const float* __restrict__ src, const float* __restrict__ w,
                            const float* __restrict__ bias, float* __restrict__ out) {
    int idx = blockIdx.x * blockDim.x + threadIdx.x;
    int wx = idx & 63;
    int hy = (idx >> 6) & 63;
    int t = idx >> 12;
    int co = t % NFC;
    int b = t / NFC;
    float acc = bias[co];
    for (int ci = 0; ci < HD; ++ci) {
        const float* sp = src + ((long)((b << 6) + ci) << 12);
        const float* wp = w + (co * HD + ci) * 9;
        #pragma unroll
        for (int kh = 0; kh < 3; ++kh) {
            int ih = hy + kh - 1;
            if (ih < 0 || ih >= HH) continue;
            #pragma unroll
            for (int kw = 0; kw < 3; ++kw) {
                int iw = wx + kw - 1;
                if (iw < 0 || iw >= WWD) continue;
                acc += sp[(ih << 6) + iw] * wp[kh * 3 + kw];
            }
        }
    }
    out[idx] = acc;
}

extern "C" void kernel_launch(void* const* d_in, const int* in_sizes, int n_in,
                              void* d_out, int out_size, void* d_ws, size_t ws_size,
                              hipStream_t stream) {
    const float* x       = (const float*)d_in[0];
    const float* enc_w   = (const float*)d_in[1];
    const float* enc_b   = (const float*)d_in[2];
    const float* enc_g   = (const float*)d_in[3];
    const float* enc_be  = (const float*)d_in[4];
    const float* in_proj = (const float*)d_in[5];
    const float* conv_w  = (const float*)d_in[6];
    const float* conv_b  = (const float*)d_in[7];
    const float* x_proj  = (const float*)d_in[8];
    const float* dt_w    = (const float*)d_in[9];
    const float* dt_b    = (const float*)d_in[10];
    const float* A_log   = (const float*)d_in[11];
    const float* Dp      = (const float*)d_in[12];
    const float* out_prj = (const float*)d_in[13];
    const float* dec1_w  = (const float*)d_in[14];
    const float* dec1_b  = (const float*)d_in[15];
    const float* dec1_g  = (const float*)d_in[16];
    const float* dec1_be = (const float*)d_in[17];
    const float* dec2_w  = (const float*)d_in[18];
    const float* dec2_b  = (const float*)d_in[19];
    float* out = (float*)d_out;

    float* ws = (float*)d_ws;
    size_t off = 0;
    float* conv_buf  = ws + off; off += 1048576;  // enc/dec scratch; Pb/hin during layers
    float* mv        = ws + off; off += 128;
    float* pbuf      = ws + off; off += 8192;
    float* wT1       = ws + off; off += 36864;
    float* t_buf     = ws + off; off += 1048576;
    float* xz_buf    = ws + off; off += 4194304;
    float* xi_buf    = ws + off; off += 2097152;
    float* xdbc_buf  = ws + off; off += 589824;
    float* delta_buf = ws + off; off += 2097152;
    float* gated_buf = ws + off; off += 2097152;  // first 1M floats double as Sb (dead before p3)
    (void)ws_size; (void)in_sizes; (void)n_in; (void)out_size;

    float* Pb = conv_buf;       // 128*4*2048 = 1048576 floats, exactly conv_buf
    float* Sb = gated_buf;      // 1048576 floats, overwritten by p3's gated output later

    // encoder
    k_enc_conv<<<4096, 256, 0, stream>>>(x, enc_w, enc_b, conv_buf);
    k_bn_stats<<<64, 256, 0, stream>>>(conv_buf, mv);
    k_bn_tr_seq<<<256, 256, 0, stream>>>(conv_buf, mv, enc_g, enc_be, t_buf);

    // mamba layers
    dim3 sg(NCHUNK, BB, 2);
    for (int i = 0; i < NLAYER; ++i) {
        k_gemm_in_t<<<512, 256, 0, stream>>>(t_buf, in_proj + (long)i * 2 * DIM * HD, xz_buf);
        k_dwconv_silu<<<MM * DIM / 256, 256, 0, stream>>>(xz_buf, conv_w + i * DIM * DCN,
                                                          conv_b + i * DIM, xi_buf);
        k_xproj_dt_t<<<512, 256, 0, stream>>>(xi_buf, x_proj + i * 36 * DIM,
                                              dt_w + i * DIM * DTRK, dt_b + i * DIM,
                                              xdbc_buf, delta_buf);
        k_scan_p1<<<sg, 256, 0, stream>>>(delta_buf, xi_buf, xdbc_buf,
                                          A_log + i * DIM * DSN, Pb, Sb);
        k_scan_p2<<<32, 256, 0, stream>>>(Pb, Sb);
        k_scan_p3<<<sg, 256, 0, stream>>>(delta_buf, xi_buf, xdbc_buf,
                                          A_log + i * DIM * DSN, Dp + i * DIM,
                                          xz_buf, Pb, gated_buf);
        k_gemm_out_t<<<512, 256, 0, stream>>>(gated_buf, out_prj + i * HD * DIM, t_buf);
    }

    // decoder
    k_prep_wdec1<<<144, 256, 0, stream>>>(dec1_w, wT1);
    dim3 dg1(64, BB);
    k_dec1_conv_t<<<dg1, 256, 0, stream>>>(t_buf, wT1, dec1_b, conv_buf);
    k_bn_stats_pm_part<<<64, 256, 0, stream>>>(conv_buf, pbuf);
    k_bn_stats_pm_fin<<<1, 64, 0, stream>>>(pbuf, mv);
    float* db_buf = t_buf;
    k_bn_tr_nchw<<<256, 256, 0, stream>>>(conv_buf, mv, dec1_g, dec1_be, db_buf);
    k_dec2_conv<<<640, 256, 0, stream>>>(db_buf, dec2_w, dec2_b, out);
}

// Round 4
// 681.098 us; speedup vs baseline: 2.4875x; 1.1222x over previous
//
#include <hip/hip_runtime.h>
#include <hip/hip_bf16.h>

// Problem constants (MinimalEventMamba)
#define BB   4
#define NBC  5
#define HD   64
#define NLAYER 4
#define NFC  10
#define DIM  128
#define DSN  16
#define DCN  4
#define DTRK 4
#define HH   64
#define WWD  64
#define LL   4096
#define MM   (BB*LL)
#define NCHUNK 128
#define CLEN   32
#define TSTEP  16

// ---------------- Encoder conv: (B,5,64,64) -> (B,64,64,64) NCHW ----------------
__global__ void k_enc_conv(const float* __restrict__ x, const float* __restrict__ w,
                           const float* __restrict__ bias, float* __restrict__ out) {
    int idx = blockIdx.x * blockDim.x + threadIdx.x;
    int wx = idx & 63;
    int hy = (idx >> 6) & 63;
    int co = (idx >> 12) & 63;
    int b  = idx >> 18;
    float acc = bias[co];
    for (int ci = 0; ci < NBC; ++ci) {
        const float* xin = x + (((long)(b * NBC + ci)) << 12);
        const float* wp  = w + (co * NBC + ci) * 9;
        #pragma unroll
        for (int kh = 0; kh < 3; ++kh) {
            int ih = hy + kh - 1;
            if (ih < 0 || ih >= HH) continue;
            #pragma unroll
            for (int kw = 0; kw < 3; ++kw) {
                int iw = wx + kw - 1;
                if (iw < 0 || iw >= WWD) continue;
                acc += xin[(ih << 6) + iw] * wp[kh * 3 + kw];
            }
        }
    }
    out[idx] = acc;
}

// ---------------- BN stats, NCHW layout (encoder path) ----------------
__global__ void k_bn_stats(const float* __restrict__ src, float* __restrict__ mv) {
    __shared__ float s1[256];
    __shared__ float s2[256];
    int c = blockIdx.x;
    int tid = threadIdx.x;
    float sum = 0.f, sq = 0.f;
    for (int i = tid; i < BB * LL; i += 256) {
        int b = i >> 12;
        int hw = i & 4095;
        float v = src[((long)((b << 6) + c) << 12) + hw];
        sum += v; sq += v * v;
    }
    s1[tid] = sum; s2[tid] = sq;
    __syncthreads();
    for (int off = 128; off > 0; off >>= 1) {
        if (tid < off) { s1[tid] += s1[tid + off]; s2[tid] += s2[tid + off]; }
        __syncthreads();
    }
    if (tid == 0) {
        float m = s1[0] * (1.f / 16384.f);
        mv[c] = m;
        mv[64 + c] = s2[0] * (1.f / 16384.f) - m * m;
    }
}

// ---------------- BN+ReLU with LDS transpose: NCHW -> seq [bhw][c] ----------------
__global__ void k_bn_tr_seq(const float* __restrict__ src, const float* __restrict__ mv,
                            const float* __restrict__ g, const float* __restrict__ be,
                            float* __restrict__ tout) {
    __shared__ float s[64 * 65];
    int blk = blockIdx.x;
    int b = blk >> 6;
    int hw0 = (blk & 63) << 6;
    int tid = threadIdx.x;
    for (int i = tid; i < 4096; i += 256) {
        int pix = i & 63, c = i >> 6;
        s[c * 65 + pix] = src[((long)((b << 6) + c) << 12) + hw0 + pix];
    }
    __syncthreads();
    for (int i = tid; i < 4096; i += 256) {
        int c = i & 63, pix = i >> 6;
        float v = s[c * 65 + pix];
        float y = (v - mv[c]) * rsqrtf(mv[64 + c] + 1e-5f) * g[c] + be[c];
        tout[((long)((b << 12) + hw0 + pix) << 6) + c] = fmaxf(y, 0.f);
    }
}

// ---------------- BN stats for pixel-major layout (two stage) ----------------
__global__ void k_bn_stats_pm_part(const float* __restrict__ src, float* __restrict__ pbuf) {
    __shared__ float s1[256], s2[256];
    int g = blockIdx.x;
    int tid = threadIdx.x;
    int c = tid & 63;
    int p = tid >> 6;
    float sum = 0.f, sq = 0.f;
    for (int row = (g << 2) + p; row < MM; row += 256) {
        float v = src[(long)row * 64 + c];
        sum += v; sq += v * v;
    }
    s1[tid] = sum; s2[tid] = sq;
    __syncthreads();
    if (p == 0) {
        sum = s1[c] + s1[64 + c] + s1[128 + c] + s1[192 + c];
        sq  = s2[c] + s2[64 + c] + s2[128 + c] + s2[192 + c];
        pbuf[(g << 6) + c] = sum;
        pbuf[4096 + (g << 6) + c] = sq;
    }
}

__global__ void k_bn_stats_pm_fin(const float* __restrict__ pbuf, float* __restrict__ mv) {
    int c = threadIdx.x;
    float s = 0.f, q = 0.f;
    for (int g = 0; g < 64; ++g) {
        s += pbuf[(g << 6) + c];
        q += pbuf[4096 + (g << 6) + c];
    }
    float m = s * (1.f / 16384.f);
    mv[c] = m;
    mv[64 + c] = q * (1.f / 16384.f) - m * m;
}

// ---------------- in_proj GEMM (M=16384,N=256,K=64), LDS tiled ----------------
__global__ void k_gemm_in_t(const float* __restrict__ tin, const float* __restrict__ Wp,
                            float* __restrict__ xz) {
    __shared__ float ts[64 * 68];
    __shared__ float w_s[128 * 68];
    int bx = blockIdx.x;
    int nh = bx & 1;
    long m0 = (long)(bx >> 1) << 6;
    int tid = threadIdx.x;
    for (int i = tid; i < 4096; i += 256) {
        int r = i >> 6, k = i & 63;
        ts[r * 68 + k] = tin[(m0 << 6) + i];
    }
    const float* wp = Wp + nh * 8192;
    for (int i = tid; i < 8192; i += 256) {
        int n = i >> 6, k = i & 63;
        w_s[n * 68 + k] = wp[i];
    }
    __syncthreads();
    int ncol = tid & 127;
    int rh = (tid >> 7) << 5;
    for (int rg = 0; rg < 4; ++rg) {
        int rbase = rh + (rg << 3);
        float acc[8] = {0,0,0,0,0,0,0,0};
        for (int k4 = 0; k4 < 16; ++k4) {
            float4 w4 = *(const float4*)&w_s[ncol * 68 + (k4 << 2)];
            #pragma unroll
            for (int r = 0; r < 8; ++r) {
                float4 a4 = *(const float4*)&ts[(rbase + r) * 68 + (k4 << 2)];
                acc[r] += a4.x * w4.x + a4.y * w4.y + a4.z * w4.z + a4.w * w4.w;
            }
        }
        #pragma unroll
        for (int r = 0; r < 8; ++r)
            xz[(m0 + rbase + r) * 256 + (nh << 7) + ncol] = acc[r];
    }
}

// ------- x_proj GEMM (N=36,K=128) + FUSED causal dwconv+SiLU + dt-proj+softplus -------
// Block = 32 seq rows. Computes xi = silu(dwconv(xz)) into LDS (and xi_buf),
// then xdbc = xi @ Wx^T, then delta = softplus(dt @ dw^T + db).
__global__ void k_xproj_fused(const float* __restrict__ xz, const float* __restrict__ cw,
                              const float* __restrict__ cb, const float* __restrict__ Wx,
                              const float* __restrict__ dw, const float* __restrict__ dbias,
                              float* __restrict__ xi, float* __restrict__ xdbc,
                              float* __restrict__ delta) {
    __shared__ float xz_s[35 * 132];
    __shared__ float xi_s[32 * 132];
    __shared__ float w_s[36 * 132];
    __shared__ float xs[32 * 40];
    __shared__ float cwT[4 * 128];
    __shared__ float cb_s[128];
    long m0 = (long)blockIdx.x << 5;
    int l0 = (int)(m0 & 4095);          // block is within one batch (4096 % 32 == 0)
    int tid = threadIdx.x;

    // stage xz halo tile (rows l0-3 .. l0+31, cols 0..127)
    for (int i = tid; i < 35 * 128; i += 256) {
        int j = i >> 7, k = i & 127;
        int l = l0 - 3 + j;
        float v = 0.f;
        if (l >= 0) v = xz[(m0 - 3 + j) * 256 + k];
        xz_s[j * 132 + k] = v;
    }
    // stage conv weights transposed [tap][di] and bias
    if (tid < 128) cb_s[tid] = cb[tid];
    for (int i = tid; i < 512; i += 256) {
        int kk = i >> 7, di = i & 127;
        cwT[(kk << 7) + di] = cw[(di << 2) + kk];
    }
    // stage GEMM weights
    for (int i = tid; i < 4608; i += 256) {
        int n = i >> 7, k = i & 127;
        w_s[n * 132 + k] = Wx[i];
    }
    __syncthreads();

    // compute xi = silu(causal dwconv) -> xi_s + global
    for (int ii = 0; ii < 4; ++ii) {
        int i = tid + (ii << 8);            // 0..1023
        int r = i >> 5;
        int d4 = (i & 31) << 2;
        float4 a = *(const float4*)&cb_s[d4];
        #pragma unroll
        for (int kk = 0; kk < 4; ++kk) {
            float4 xv = *(const float4*)&xz_s[(r + kk) * 132 + d4];
            float4 wv = *(const float4*)&cwT[(kk << 7) + d4];
            a.x += xv.x * wv.x; a.y += xv.y * wv.y;
            a.z += xv.z * wv.z; a.w += xv.w * wv.w;
        }
        a.x = a.x / (1.f + __expf(-a.x));
        a.y = a.y / (1.f + __expf(-a.y));
        a.z = a.z / (1.f + __expf(-a.z));
        a.w = a.w / (1.f + __expf(-a.w));
        *(float4*)&xi_s[r * 132 + d4] = a;
        *(float4*)&xi[(m0 + r) * 128 + d4] = a;
    }
    __syncthreads();

    // GEMM: xdbc[m, n<36] = xi_s . w_s
    int n = tid & 63;
    int rg = tid >> 6;
    if (n < 36) {
        float acc[8] = {0,0,0,0,0,0,0,0};
        for (int k4 = 0; k4 < 32; ++k4) {
            float4 w4 = *(const float4*)&w_s[n * 132 + (k4 << 2)];
            #pragma unroll
            for (int r = 0; r < 8; ++r) {
                float4 a4 = *(const float4*)&xi_s[((rg << 3) + r) * 132 + (k4 << 2)];
                acc[r] += a4.x * w4.x + a4.y * w4.y + a4.z * w4.z + a4.w * w4.w;
            }
        }
        #pragma unroll
        for (int r = 0; r < 8; ++r) {
            int rr = (rg << 3) + r;
            xdbc[(m0 + rr) * 36 + n] = acc[r];
            xs[rr * 40 + n] = acc[r];
        }
    }
    __syncthreads();
    for (int i = tid; i < 4096; i += 256) {
        int r = i >> 7, di = i & 127;
        float v = dbias[di];
        float4 d4 = *(const float4*)&dw[di << 2];
        v += xs[r * 40 + 0] * d4.x + xs[r * 40 + 1] * d4.y
           + xs[r * 40 + 2] * d4.z + xs[r * 40 + 3] * d4.w;
        delta[(m0 + r) * 128 + di] = (v > 20.f) ? v : log1pf(expf(v));
    }
}

// ---------------- selective scan, chunked, 4 ds-states per thread ----------------
__global__ void k_scan_p1(const float* __restrict__ delta, const float* __restrict__ xi,
                          const float* __restrict__ xdbc, const float* __restrict__ A_log,
                          float* __restrict__ Pb, float* __restrict__ Sb) {
    __shared__ float d_s[TSTEP][64];
    __shared__ float u_s[TSTEP][64];
    __shared__ float b_s[TSTEP][16];
    int chunk = blockIdx.x, b = blockIdx.y, half = blockIdx.z;
    int tid = threadIdx.x;
    int dq = tid & 3;
    int dil = tid >> 2;
    int di = (half << 6) + dil;
    float4 al = *(const float4*)&A_log[(di << 4) + (dq << 2)];
    float Av[4] = { -expf(al.x), -expf(al.y), -expf(al.z), -expf(al.w) };
    float h[4] = {0.f, 0.f, 0.f, 0.f};
    float P[4] = {1.f, 1.f, 1.f, 1.f};
    long t0 = ((long)b << 12) + (long)chunk * CLEN;

    int srow = tid >> 4, sc4 = (tid & 15) << 2;
    for (int tile = 0; tile < CLEN / TSTEP; ++tile) {
        __syncthreads();
        long ls = t0 + tile * TSTEP + srow;
        *(float4*)&d_s[srow][sc4] = *(const float4*)&delta[(ls << 7) + (half << 6) + sc4];
        *(float4*)&u_s[srow][sc4] = *(const float4*)&xi[(ls << 7) + (half << 6) + sc4];
        if (tid < 64) {
            int r2 = tid >> 2, cc = (tid & 3) << 2;
            long l2 = t0 + tile * TSTEP + r2;
            *(float4*)&b_s[r2][cc] = *(const float4*)&xdbc[l2 * 36 + DTRK + cc];
        }
        __syncthreads();
        #pragma unroll
        for (int i = 0; i < TSTEP; ++i) {
            float d = d_s[i][dil];
            float u = u_s[i][dil];
            float du = d * u;
            float4 Bv = *(float4*)&b_s[i][dq << 2];
            float a0 = __expf(d * Av[0]); h[0] = a0 * h[0] + du * Bv.x; P[0] *= a0;
            float a1 = __expf(d * Av[1]); h[1] = a1 * h[1] + du * Bv.y; P[1] *= a1;
            float a2 = __expf(d * Av[2]); h[2] = a2 * h[2] + du * Bv.z; P[2] *= a2;
            float a3 = __expf(d * Av[3]); h[3] = a3 * h[3] + du * Bv.w; P[3] *= a3;
        }
    }
    long o = (((long)chunk * BB + b) << 11) + (di << 4) + (dq << 2);
    *(float4*)&Pb[o] = make_float4(P[0], P[1], P[2], P[3]);
    *(float4*)&Sb[o] = make_float4(h[0], h[1], h[2], h[3]);
}

__global__ void k_scan_p2(float* Pb, const float* __restrict__ Sb) {
    int t = blockIdx.x * blockDim.x + threadIdx.x;
    int b = t >> 11;
    int s = t & 2047;
    float h = 0.f;
    for (int c = 0; c < NCHUNK; ++c) {
        long idx = (((long)c * BB + b) << 11) + s;
        float p = Pb[idx];
        float sv = Sb[idx];
        Pb[idx] = h;
        h = p * h + sv;
    }
}

__global__ void k_scan_p3(const float* __restrict__ delta, const float* __restrict__ xi,
                          const float* __restrict__ xdbc, const float* __restrict__ A_log,
                          const float* __restrict__ Dp, const float* __restrict__ xz,
                          const float* __restrict__ hin, float* __restrict__ gated) {
    __shared__ float d_s[TSTEP][64];
    __shared__ float u_s[TSTEP][64];
    __shared__ float bc_s[TSTEP][32];
    __shared__ float y_s[TSTEP][64];
    int chunk = blockIdx.x, b = blockIdx.y, half = blockIdx.z;
    int tid = threadIdx.x;
    int dq = tid & 3;
    int dil = tid >> 2;
    int di = (half << 6) + dil;
    float4 al = *(const float4*)&A_log[(di << 4) + (dq << 2)];
    float Av[4] = { -expf(al.x), -expf(al.y), -expf(al.z), -expf(al.w) };
    float Dv = Dp[di];
    long ho = (((long)chunk * BB + b) << 11) + (di << 4) + (dq << 2);
    float4 h4 = *(const float4*)&hin[ho];
    float h[4] = { h4.x, h4.y, h4.z, h4.w };
    long t0 = ((long)b << 12) + (long)chunk * CLEN;

    int srow = tid >> 4, sc4 = (tid & 15) << 2;
    for (int tile = 0; tile < CLEN / TSTEP; ++tile) {
        __syncthreads();
        long ls = t0 + tile * TSTEP + srow;
        *(float4*)&d_s[srow][sc4] = *(const float4*)&delta[(ls << 7) + (half << 6) + sc4];
        *(float4*)&u_s[srow][sc4] = *(const float4*)&xi[(ls << 7) + (half << 6) + sc4];
        if (tid < 128) {
            int r2 = tid >> 3, cc = (tid & 7) << 2;
            long l2 = t0 + tile * TSTEP + r2;
            *(float4*)&bc_s[r2][cc] = *(const float4*)&xdbc[l2 * 36 + DTRK + cc];
        }
        __syncthreads();
        #pragma unroll
        for (int i = 0; i < TSTEP; ++i) {
            float d = d_s[i][dil];
            float u = u_s[i][dil];
            float du = d * u;
            float4 Bv = *(float4*)&bc_s[i][dq << 2];
            float4 Cv = *(float4*)&bc_s[i][16 + (dq << 2)];
            float a0 = __expf(d * Av[0]); h[0] = a0 * h[0] + du * Bv.x;
            float a1 = __expf(d * Av[1]); h[1] = a1 * h[1] + du * Bv.y;
            float a2 = __expf(d * Av[2]); h[2] = a2 * h[2] + du * Bv.z;
            float a3 = __expf(d * Av[3]); h[3] = a3 * h[3] + du * Bv.w;
            float yp = h[0] * Cv.x + h[1] * Cv.y + h[2] * Cv.z + h[3] * Cv.w;
            yp += __shfl_xor(yp, 1);
            yp += __shfl_xor(yp, 2);
            if (dq == 0)
                y_s[i][dil] = yp + u * Dv;
        }
        __syncthreads();
        {
            long l = t0 + tile * TSTEP + srow;
            float4 y4 = *(float4*)&y_s[srow][sc4];
            float4 z4 = *(const float4*)&xz[(l << 8) + DIM + (half << 6) + sc4];
            float4 o;
            o.x = y4.x * (z4.x / (1.f + __expf(-z4.x)));
            o.y = y4.y * (z4.y / (1.f + __expf(-z4.y)));
            o.z = y4.z * (z4.z / (1.f + __expf(-z4.z)));
            o.w = y4.w * (z4.w / (1.f + __expf(-z4.w)));
            *(float4*)&gated[(l << 7) + (half << 6) + sc4] = o;
        }
    }
}

// ---------------- out_proj GEMM (N=64,K=128) + residual, LDS tiled ----------------
__global__ void k_gemm_out_t(const float* __restrict__ gated, const float* __restrict__ Wo,
                             float* __restrict__ tio) {
    __shared__ float ts[32 * 132];
    __shared__ float w_s[64 * 132];
    long m0 = (long)blockIdx.x << 5;
    int tid = threadIdx.x;
    for (int i = tid; i < 4096; i += 256) {
        int r = i >> 7, k = i & 127;
        ts[r * 132 + k] = gated[(m0 << 7) + i];
    }
    for (int i = tid; i < 8192; i += 256) {
        int nn = i >> 7, k = i & 127;
        w_s[nn * 132 + k] = Wo[i];
    }
    __syncthreads();
    int n = tid & 63;
    int rg = tid >> 6;
    float acc[8] = {0,0,0,0,0,0,0,0};
    for (int k4 = 0; k4 < 32; ++k4) {
        float4 w4 = *(const float4*)&w_s[n * 132 + (k4 << 2)];
        #pragma unroll
        for (int r = 0; r < 8; ++r) {
            float4 a4 = *(const float4*)&ts[((rg << 3) + r) * 132 + (k4 << 2)];
            acc[r] += a4.x * w4.x + a4.y * w4.y + a4.z * w4.z + a4.w * w4.w;
        }
    }
    #pragma unroll
    for (int r = 0; r < 8; ++r) {
        long m = m0 + (rg << 3) + r;
        tio[m * 64 + n] += acc[r];
    }
}

// ---------------- dec1 weight transpose: [co][ci][tap] -> [tap][ci][co] ----------------
__global__ void k_prep_wdec1(const float* __restrict__ w, float* __restrict__ wT) {
    int idx = blockIdx.x * blockDim.x + threadIdx.x;
    int co = idx & 63;
    int ci = (idx >> 6) & 63;
    int tap = idx >> 12;
    wT[idx] = w[co * 576 + ci * 9 + tap];
}

// ---------------- dec2 weight transpose: [co][ci][tap9] -> [ci][co][tap12] ----------------
__global__ void k_prep_wdec2(const float* __restrict__ w, float* __restrict__ wT) {
    int idx = blockIdx.x * blockDim.x + threadIdx.x;   // 7680
    if (idx >= 64 * NFC * 12) return;
    int tap = idx % 12;
    int t2 = idx / 12;
    int co = t2 % NFC;
    int ci = t2 / NFC;
    wT[idx] = (tap < 9) ? w[co * 576 + ci * 9 + tap] : 0.f;
}

// ---------------- decoder conv1, LDS tiled ----------------
__global__ void k_dec1_conv_t(const float* __restrict__ tin, const float* __restrict__ wT,
                              const float* __restrict__ bias, float* __restrict__ out) {
    __shared__ float x_s[64 * 101];
    __shared__ float w_s[64 * 64];
    int tile = blockIdx.x;
    int b = blockIdx.y;
    int ty0 = (tile >> 3) << 3;
    int tx0 = (tile & 7) << 3;
    int tid = threadIdx.x;

    for (int i = tid; i < 6400; i += 256) {
        int pl = i >> 6;
        int c = i & 63;
        int py = pl / 10, px = pl - py * 10;
        int ih = ty0 + py - 1, iw = tx0 + px - 1;
        float v = 0.f;
        if (ih >= 0 && ih < HH && iw >= 0 && iw < WWD)
            v = tin[((long)((b << 12) + (ih << 6) + iw)) * 64 + c];
        x_s[c * 101 + pl] = v;
    }

    int p4 = tid & 15;
    int c4 = tid >> 4;
    int py = p4 >> 1;
    int px2 = (p4 & 1) << 2;
    float acc[4][4];
    #pragma unroll
    for (int j = 0; j < 4; ++j)
        #pragma unroll
        for (int co = 0; co < 4; ++co) acc[j][co] = 0.f;

    for (int tap = 0; tap < 9; ++tap) {
        __syncthreads();
        for (int i = tid; i < 4096; i += 256)
            w_s[i] = wT[tap * 4096 + i];
        __syncthreads();
        int kh = tap / 3, kw = tap - kh * 3;
        int xbase = (py + kh) * 10 + px2 + kw;
        for (int ci = 0; ci < 64; ++ci) {
            float4 w4 = *(const float4*)&w_s[(ci << 6) + (c4 << 2)];
            const float* xr = &x_s[ci * 101 + xbase];
            #pragma unroll
            for (int j = 0; j < 4; ++j) {
                float xv = xr[j];
                acc[j][0] += xv * w4.x;
                acc[j][1] += xv * w4.y;
                acc[j][2] += xv * w4.z;
                acc[j][3] += xv * w4.w;
            }
        }
    }
    float4 bv = *(const float4*)&bias[c4 << 2];
    #pragma unroll
    for (int j = 0; j < 4; ++j) {
        int hw = ((ty0 + py) << 6) + tx0 + px2 + j;
        float4 o;
        o.x = acc[j][0] + bv.x; o.y = acc[j][1] + bv.y;
        o.z = acc[j][2] + bv.z; o.w = acc[j][3] + bv.w;
        *(float4*)&out[((long)((b << 12) + hw)) * 64 + (c4 << 2)] = o;
    }
}

// ------- decoder conv2 FUSED with BN+ReLU: pixel-major (B,4096,64) -> NCHW (B,10,64,64) -------
// grid (64 tiles, B), 256 threads = 64 px x 4 co-groups; co = cog + 4*j (j<3, skip >=10).
__global__ void k_dec2_fused(const float* __restrict__ src, const float* __restrict__ mv,
                             const float* __restrict__ g, const float* __restrict__ be,
                             const float* __restrict__ wT, const float* __restrict__ bias,
                             float* __restrict__ out) {
    __shared__ float x_s[64 * 101];
    __shared__ float w_s[64 * NFC * 12];
    __shared__ float sc_s[64];
    __shared__ float sh_s[64];
    int tile = blockIdx.x;
    int b = blockIdx.y;
    int ty0 = (tile >> 3) << 3;
    int tx0 = (tile & 7) << 3;
    int tid = threadIdx.x;

    if (tid < 64) {
        float m = mv[tid], v = mv[64 + tid];
        float s = g[tid] * rsqrtf(v + 1e-5f);
        sc_s[tid] = s;
        sh_s[tid] = be[tid] - m * s;
    }
    for (int i = tid; i < 64 * NFC * 12; i += 256)
        w_s[i] = wT[i];
    __syncthreads();

    for (int i = tid; i < 6400; i += 256) {
        int pl = i >> 6;
        int c = i & 63;
        int py = pl / 10, px = pl - py * 10;
        int ih = ty0 + py - 1, iw = tx0 + px - 1;
        float v = 0.f;
        if (ih >= 0 && ih < HH && iw >= 0 && iw < WWD) {
            v = src[((long)((b << 12) + (ih << 6) + iw)) * 64 + c];
            v = fmaxf(v * sc_s[c] + sh_s[c], 0.f);
        }
        x_s[c * 101 + pl] = v;
    }
    __syncthreads();

    int px = tid & 63;
    int py = px >> 3, pxx = px & 7;
    int cog = tid >> 6;
    float acc[3] = {0.f, 0.f, 0.f};
    int nco = (cog < 2) ? 3 : 2;       // co = cog, cog+4, cog+8 (cog+8 < 10 only for cog<2)

    for (int ci = 0; ci < 64; ++ci) {
        const float* xr = &x_s[ci * 101 + py * 10 + pxx];
        float xv[9];
        #pragma unroll
        for (int kh = 0; kh < 3; ++kh)
            #pragma unroll
            for (int kw = 0; kw < 3; ++kw)
                xv[kh * 3 + kw] = xr[kh * 10 + kw];
        #pragma unroll
        for (int j = 0; j < 3; ++j) {
            if (j >= nco) break;
            int co = cog + (j << 2);
            const float* wp = &w_s[(ci * NFC + co) * 12];
            float4 w0 = *(const float4*)&wp[0];
            float4 w1 = *(const float4*)&wp[4];
            float  w8 = wp[8];
            acc[j] += xv[0] * w0.x + xv[1] * w0.y + xv[2] * w0.z + xv[3] * w0.w
                    + xv[4] * w1.x + xv[5] * w1.y + xv[6] * w1.z + xv[7] * w1.w
                    + xv[8] * w8;
        }
    }
    int hw = ((ty0 + py) << 6) + tx0 + pxx;
    #pragma unroll
    for (int j = 0; j < 3; ++j) {
        if (j >= nco) break;
        int co = cog + (j << 2);
        out[((long)(b * NFC + co) << 12) + hw] = acc[j] + bias[co];
    }
}

extern "C" void kernel_launch(void* const* d_in, const int* in_sizes, int n_in,
                              void* d_out, int out_size, void* d_ws, size_t ws_size,
                              hipStream_t stream) {
    const float* x       = (const float*)d_in[0];
    const float* enc_w   = (const float*)d_in[1];
    const float* enc_b   = (const float*)d_in[2];
    const float* enc_g   = (const float*)d_in[3];
    const float* enc_be  = (const float*)d_in[4];
    const float* in_proj = (const float*)d_in[5];
    const float* conv_w  = (const float*)d_in[6];
    const float* conv_b  = (const float*)d_in[7];
    const float* x_proj  = (const float*)d_in[8];
    const float* dt_w    = (const float*)d_in[9];
    const float* dt_b    = (const float*)d_in[10];
    const float* A_log   = (const float*)d_in[11];
    const float* Dp      = (const float*)d_in[12];
    const float* out_prj = (const float*)d_in[13];
    const float* dec1_w  = (const float*)d_in[14];
    const float* dec1_b  = (const float*)d_in[15];
    const float* dec1_g  = (const float*)d_in[16];
    const float* dec1_be = (const float*)d_in[17];
    const float* dec2_w  = (const float*)d_in[18];
    const float* dec2_b  = (const float*)d_in[19];
    float* out = (float*)d_out;

    float* ws = (float*)d_ws;
    size_t off = 0;
    float* conv_buf  = ws + off; off += 1048576;  // enc/dec scratch; Pb/hin during layers
    float* mv        = ws + off; off += 128;
    float* pbuf      = ws + off; off += 8192;
    float* wT1       = ws + off; off += 36864;
    float* wT2       = ws + off; off += 7680;
    float* t_buf     = ws + off; off += 1048576;
    float* xz_buf    = ws + off; off += 4194304;
    float* xi_buf    = ws + off; off += 2097152;
    float* xdbc_buf  = ws + off; off += 589824;
    float* delta_buf = ws + off; off += 2097152;
    float* gated_buf = ws + off; off += 2097152;  // first 1M floats double as Sb
    (void)ws_size; (void)in_sizes; (void)n_in; (void)out_size;

    float* Pb = conv_buf;
    float* Sb = gated_buf;

    // encoder
    k_enc_conv<<<4096, 256, 0, stream>>>(x, enc_w, enc_b, conv_buf);
    k_bn_stats<<<64, 256, 0, stream>>>(conv_buf, mv);
    k_bn_tr_seq<<<256, 256, 0, stream>>>(conv_buf, mv, enc_g, enc_be, t_buf);

    // mamba layers
    dim3 sg(NCHUNK, BB, 2);
    for (int i = 0; i < NLAYER; ++i) {
        k_gemm_in_t<<<512, 256, 0, stream>>>(t_buf, in_proj + (long)i * 2 * DIM * HD, xz_buf);
        k_xproj_fused<<<512, 256, 0, stream>>>(xz_buf, conv_w + i * DIM * DCN,
                                               conv_b + i * DIM, x_proj + i * 36 * DIM,
                                               dt_w + i * DIM * DTRK, dt_b + i * DIM,
                                               xi_buf, xdbc_buf, delta_buf);
        k_scan_p1<<<sg, 256, 0, stream>>>(delta_buf, xi_buf, xdbc_buf,
                                          A_log + i * DIM * DSN, Pb, Sb);
        k_scan_p2<<<32, 256, 0, stream>>>(Pb, Sb);
        k_scan_p3<<<sg, 256, 0, stream>>>(delta_buf, xi_buf, xdbc_buf,
                                          A_log + i * DIM * DSN, Dp + i * DIM,
                                          xz_buf, Pb, gated_buf);
        k_gemm_out_t<<<512, 256, 0, stream>>>(gated_buf, out_prj + i * HD * DIM, t_buf);
    }

    // decoder
    k_prep_wdec1<<<144, 256, 0, stream>>>(dec1_w, wT1);
    k_prep_wdec2<<<30, 256, 0, stream>>>(dec2_w, wT2);
    dim3 dg1(64, BB);
    k_dec1_conv_t<<<dg1, 256, 0, stream>>>(t_buf, wT1, dec1_b, conv_buf);
    k_bn_stats_pm_part<<<64, 256, 0, stream>>>(conv_buf, pbuf);
    k_bn_stats_pm_fin<<<1, 64, 0, stream>>>(pbuf, mv);
    k_dec2_fused<<<dg1, 256, 0, stream>>>(conv_buf, mv, dec1_g, dec1_be, wT2, dec2_b, out);
}

// Round 5
// 565.783 us; speedup vs baseline: 2.9945x; 1.2038x over previous
//
#include <hip/hip_runtime.h>
#include <hip/hip_bf16.h>

// Problem constants (MinimalEventMamba)
#define BB   4
#define NBC  5
#define HD   64
#define NLAYER 4
#define NFC  10
#define DIM  128
#define DSN  16
#define DCN  4
#define DTRK 4
#define HH   64
#define WWD  64
#define LL   4096
#define MM   (BB*LL)
#define NCHUNK 128
#define CLEN   32
#define TSTEP  16

// ---------------- Encoder conv: (B,5,64,64) -> (B,64,64,64) NCHW ----------------
__global__ void k_enc_conv(const float* __restrict__ x, const float* __restrict__ w,
                           const float* __restrict__ bias, float* __restrict__ out) {
    int idx = blockIdx.x * blockDim.x + threadIdx.x;
    int wx = idx & 63;
    int hy = (idx >> 6) & 63;
    int co = (idx >> 12) & 63;
    int b  = idx >> 18;
    float acc = bias[co];
    for (int ci = 0; ci < NBC; ++ci) {
        const float* xin = x + (((long)(b * NBC + ci)) << 12);
        const float* wp  = w + (co * NBC + ci) * 9;
        #pragma unroll
        for (int kh = 0; kh < 3; ++kh) {
            int ih = hy + kh - 1;
            if (ih < 0 || ih >= HH) continue;
            #pragma unroll
            for (int kw = 0; kw < 3; ++kw) {
                int iw = wx + kw - 1;
                if (iw < 0 || iw >= WWD) continue;
                acc += xin[(ih << 6) + iw] * wp[kh * 3 + kw];
            }
        }
    }
    out[idx] = acc;
}

// ---------------- BN stats, NCHW layout (encoder path) ----------------
__global__ void k_bn_stats(const float* __restrict__ src, float* __restrict__ mv) {
    __shared__ float s1[256];
    __shared__ float s2[256];
    int c = blockIdx.x;
    int tid = threadIdx.x;
    float sum = 0.f, sq = 0.f;
    for (int i = tid; i < BB * LL; i += 256) {
        int b = i >> 12;
        int hw = i & 4095;
        float v = src[((long)((b << 6) + c) << 12) + hw];
        sum += v; sq += v * v;
    }
    s1[tid] = sum; s2[tid] = sq;
    __syncthreads();
    for (int off = 128; off > 0; off >>= 1) {
        if (tid < off) { s1[tid] += s1[tid + off]; s2[tid] += s2[tid + off]; }
        __syncthreads();
    }
    if (tid == 0) {
        float m = s1[0] * (1.f / 16384.f);
        mv[c] = m;
        mv[64 + c] = s2[0] * (1.f / 16384.f) - m * m;
    }
}

// ---------------- BN+ReLU with LDS transpose: NCHW -> seq [bhw][c] ----------------
__global__ void k_bn_tr_seq(const float* __restrict__ src, const float* __restrict__ mv,
                            const float* __restrict__ g, const float* __restrict__ be,
                            float* __restrict__ tout) {
    __shared__ float s[64 * 65];
    int blk = blockIdx.x;
    int b = blk >> 6;
    int hw0 = (blk & 63) << 6;
    int tid = threadIdx.x;
    for (int i = tid; i < 4096; i += 256) {
        int pix = i & 63, c = i >> 6;
        s[c * 65 + pix] = src[((long)((b << 6) + c) << 12) + hw0 + pix];
    }
    __syncthreads();
    for (int i = tid; i < 4096; i += 256) {
        int c = i & 63, pix = i >> 6;
        float v = s[c * 65 + pix];
        float y = (v - mv[c]) * rsqrtf(mv[64 + c] + 1e-5f) * g[c] + be[c];
        tout[((long)((b << 12) + hw0 + pix) << 6) + c] = fmaxf(y, 0.f);
    }
}

// ---------------- BN stats for pixel-major layout (two stage) ----------------
__global__ void k_bn_stats_pm_part(const float* __restrict__ src, float* __restrict__ pbuf) {
    __shared__ float s1[256], s2[256];
    int g = blockIdx.x;
    int tid = threadIdx.x;
    int c = tid & 63;
    int p = tid >> 6;
    float sum = 0.f, sq = 0.f;
    for (int row = (g << 2) + p; row < MM; row += 256) {
        float v = src[(long)row * 64 + c];
        sum += v; sq += v * v;
    }
    s1[tid] = sum; s2[tid] = sq;
    __syncthreads();
    if (p == 0) {
        sum = s1[c] + s1[64 + c] + s1[128 + c] + s1[192 + c];
        sq  = s2[c] + s2[64 + c] + s2[128 + c] + s2[192 + c];
        pbuf[(g << 6) + c] = sum;
        pbuf[4096 + (g << 6) + c] = sq;
    }
}

__global__ void k_bn_stats_pm_fin(const float* __restrict__ pbuf, float* __restrict__ mv) {
    int c = threadIdx.x;
    float s = 0.f, q = 0.f;
    for (int g = 0; g < 64; ++g) {
        s += pbuf[(g << 6) + c];
        q += pbuf[4096 + (g << 6) + c];
    }
    float m = s * (1.f / 16384.f);
    mv[c] = m;
    mv[64 + c] = q * (1.f / 16384.f) - m * m;
}

// ---------------- weight pre-transposes for the GEMMs: wT[k][n] ----------------
__global__ void k_prep_wt(const float* __restrict__ in_proj, const float* __restrict__ out_proj,
                          float* __restrict__ wTin, float* __restrict__ wTout) {
    int idx = blockIdx.x * blockDim.x + threadIdx.x;   // 98304
    if (idx < 65536) {
        int n = idx & 255, k = (idx >> 8) & 63, l = idx >> 14;
        wTin[idx] = in_proj[(l << 14) + (n << 6) + k];
    } else {
        int j = idx - 65536;
        int n = j & 63, k = (j >> 6) & 127, l = j >> 13;
        wTout[j] = out_proj[(l << 13) + (n << 7) + k];
    }
}

// ---------------- in_proj GEMM (M=16384,N=256,K=64): 8x8 register tile ----------------
// A staged in LDS; W streamed from global wT[k][n] (L2-resident, coalesced).
__global__ __launch_bounds__(256, 1) void k_gemm_in2(const float* __restrict__ tin,
                                                     const float* __restrict__ wT,
                                                     float* __restrict__ xz) {
    __shared__ __align__(16) float ts[64 * 68];
    long m0 = (long)blockIdx.x << 6;
    int tid = threadIdx.x;
    int rg = tid >> 5;          // 8 groups of 8 rows
    int cg = tid & 31;          // 32 groups of 8 cols
    for (int i = tid; i < 4096; i += 256) {
        int r = i >> 6, k = i & 63;
        ts[r * 68 + k] = tin[(m0 << 6) + i];
    }
    __syncthreads();
    float acc[8][8] = {};
    int n0 = cg << 3;
    for (int k4 = 0; k4 < 16; ++k4) {
        float4 a[8];
        #pragma unroll
        for (int r2 = 0; r2 < 8; ++r2)
            a[r2] = *(const float4*)&ts[((rg << 3) + r2) * 68 + (k4 << 2)];
        #pragma unroll
        for (int kk = 0; kk < 4; ++kk) {
            const float* wr = wT + (((k4 << 2) + kk) << 8) + n0;
            float4 w0 = *(const float4*)&wr[0];
            float4 w1 = *(const float4*)&wr[4];
            #pragma unroll
            for (int r2 = 0; r2 < 8; ++r2) {
                float av = (kk == 0) ? a[r2].x : (kk == 1) ? a[r2].y
                         : (kk == 2) ? a[r2].z : a[r2].w;
                acc[r2][0] += av * w0.x; acc[r2][1] += av * w0.y;
                acc[r2][2] += av * w0.z; acc[r2][3] += av * w0.w;
                acc[r2][4] += av * w1.x; acc[r2][5] += av * w1.y;
                acc[r2][6] += av * w1.z; acc[r2][7] += av * w1.w;
            }
        }
    }
    #pragma unroll
    for (int r2 = 0; r2 < 8; ++r2) {
        long m = m0 + (rg << 3) + r2;
        *(float4*)&xz[(m << 8) + n0]     = make_float4(acc[r2][0], acc[r2][1], acc[r2][2], acc[r2][3]);
        *(float4*)&xz[(m << 8) + n0 + 4] = make_float4(acc[r2][4], acc[r2][5], acc[r2][6], acc[r2][7]);
    }
}

// ------- x_proj GEMM (N=36,K=128) + FUSED causal dwconv+SiLU + dt-proj+softplus -------
__global__ void k_xproj_fused(const float* __restrict__ xz, const float* __restrict__ cw,
                              const float* __restrict__ cb, const float* __restrict__ Wx,
                              const float* __restrict__ dw, const float* __restrict__ dbias,
                              float* __restrict__ xi, float* __restrict__ xdbc,
                              float* __restrict__ delta) {
    __shared__ float xz_s[35 * 132];
    __shared__ float xi_s[32 * 132];
    __shared__ float w_s[36 * 132];
    __shared__ float xs[32 * 40];
    __shared__ float cwT[4 * 128];
    __shared__ float cb_s[128];
    long m0 = (long)blockIdx.x << 5;
    int l0 = (int)(m0 & 4095);
    int tid = threadIdx.x;

    for (int i = tid; i < 35 * 128; i += 256) {
        int j = i >> 7, k = i & 127;
        int l = l0 - 3 + j;
        float v = 0.f;
        if (l >= 0) v = xz[(m0 - 3 + j) * 256 + k];
        xz_s[j * 132 + k] = v;
    }
    if (tid < 128) cb_s[tid] = cb[tid];
    for (int i = tid; i < 512; i += 256) {
        int kk = i >> 7, di = i & 127;
        cwT[(kk << 7) + di] = cw[(di << 2) + kk];
    }
    for (int i = tid; i < 4608; i += 256) {
        int n = i >> 7, k = i & 127;
        w_s[n * 132 + k] = Wx[i];
    }
    __syncthreads();

    for (int ii = 0; ii < 4; ++ii) {
        int i = tid + (ii << 8);
        int r = i >> 5;
        int d4 = (i & 31) << 2;
        float4 a = *(const float4*)&cb_s[d4];
        #pragma unroll
        for (int kk = 0; kk < 4; ++kk) {
            float4 xv = *(const float4*)&xz_s[(r + kk) * 132 + d4];
            float4 wv = *(const float4*)&cwT[(kk << 7) + d4];
            a.x += xv.x * wv.x; a.y += xv.y * wv.y;
            a.z += xv.z * wv.z; a.w += xv.w * wv.w;
        }
        a.x = a.x / (1.f + __expf(-a.x));
        a.y = a.y / (1.f + __expf(-a.y));
        a.z = a.z / (1.f + __expf(-a.z));
        a.w = a.w / (1.f + __expf(-a.w));
        *(float4*)&xi_s[r * 132 + d4] = a;
        *(float4*)&xi[(m0 + r) * 128 + d4] = a;
    }
    __syncthreads();

    int n = tid & 63;
    int rg = tid >> 6;
    if (n < 36) {
        float acc[8] = {0,0,0,0,0,0,0,0};
        for (int k4 = 0; k4 < 32; ++k4) {
            float4 w4 = *(const float4*)&w_s[n * 132 + (k4 << 2)];
            #pragma unroll
            for (int r = 0; r < 8; ++r) {
                float4 a4 = *(const float4*)&xi_s[((rg << 3) + r) * 132 + (k4 << 2)];
                acc[r] += a4.x * w4.x + a4.y * w4.y + a4.z * w4.z + a4.w * w4.w;
            }
        }
        #pragma unroll
        for (int r = 0; r < 8; ++r) {
            int rr = (rg << 3) + r;
            xdbc[(m0 + rr) * 36 + n] = acc[r];
            xs[rr * 40 + n] = acc[r];
        }
    }
    __syncthreads();
    for (int i = tid; i < 4096; i += 256) {
        int r = i >> 7, di = i & 127;
        float v = dbias[di];
        float4 d4 = *(const float4*)&dw[di << 2];
        v += xs[r * 40 + 0] * d4.x + xs[r * 40 + 1] * d4.y
           + xs[r * 40 + 2] * d4.z + xs[r * 40 + 3] * d4.w;
        delta[(m0 + r) * 128 + di] = (v > 20.f) ? v : log1pf(expf(v));
    }
}

// ---------------- selective scan, chunked, 4 ds-states per thread ----------------
__global__ void k_scan_p1(const float* __restrict__ delta, const float* __restrict__ xi,
                          const float* __restrict__ xdbc, const float* __restrict__ A_log,
                          float* __restrict__ Pb, float* __restrict__ Sb) {
    __shared__ float d_s[TSTEP][64];
    __shared__ float u_s[TSTEP][64];
    __shared__ float b_s[TSTEP][16];
    int chunk = blockIdx.x, b = blockIdx.y, half = blockIdx.z;
    int tid = threadIdx.x;
    int dq = tid & 3;
    int dil = tid >> 2;
    int di = (half << 6) + dil;
    float4 al = *(const float4*)&A_log[(di << 4) + (dq << 2)];
    float Av[4] = { -expf(al.x), -expf(al.y), -expf(al.z), -expf(al.w) };
    float h[4] = {0.f, 0.f, 0.f, 0.f};
    float P[4] = {1.f, 1.f, 1.f, 1.f};
    long t0 = ((long)b << 12) + (long)chunk * CLEN;

    int srow = tid >> 4, sc4 = (tid & 15) << 2;
    for (int tile = 0; tile < CLEN / TSTEP; ++tile) {
        __syncthreads();
        long ls = t0 + tile * TSTEP + srow;
        *(float4*)&d_s[srow][sc4] = *(const float4*)&delta[(ls << 7) + (half << 6) + sc4];
        *(float4*)&u_s[srow][sc4] = *(const float4*)&xi[(ls << 7) + (half << 6) + sc4];
        if (tid < 64) {
            int r2 = tid >> 2, cc = (tid & 3) << 2;
            long l2 = t0 + tile * TSTEP + r2;
            *(float4*)&b_s[r2][cc] = *(const float4*)&xdbc[l2 * 36 + DTRK + cc];
        }
        __syncthreads();
        #pragma unroll
        for (int i = 0; i < TSTEP; ++i) {
            float d = d_s[i][dil];
            float u = u_s[i][dil];
            float du = d * u;
            float4 Bv = *(float4*)&b_s[i][dq << 2];
            float a0 = __expf(d * Av[0]); h[0] = a0 * h[0] + du * Bv.x; P[0] *= a0;
            float a1 = __expf(d * Av[1]); h[1] = a1 * h[1] + du * Bv.y; P[1] *= a1;
            float a2 = __expf(d * Av[2]); h[2] = a2 * h[2] + du * Bv.z; P[2] *= a2;
            float a3 = __expf(d * Av[3]); h[3] = a3 * h[3] + du * Bv.w; P[3] *= a3;
        }
    }
    long o = (((long)chunk * BB + b) << 11) + (di << 4) + (dq << 2);
    *(float4*)&Pb[o] = make_float4(P[0], P[1], P[2], P[3]);
    *(float4*)&Sb[o] = make_float4(h[0], h[1], h[2], h[3]);
}

__global__ void k_scan_p2(float* Pb, const float* __restrict__ Sb) {
    int t = blockIdx.x * blockDim.x + threadIdx.x;
    int b = t >> 11;
    int s = t & 2047;
    float h = 0.f;
    for (int c = 0; c < NCHUNK; ++c) {
        long idx = (((long)c * BB + b) << 11) + s;
        float p = Pb[idx];
        float sv = Sb[idx];
        Pb[idx] = h;
        h = p * h + sv;
    }
}

__global__ void k_scan_p3(const float* __restrict__ delta, const float* __restrict__ xi,
                          const float* __restrict__ xdbc, const float* __restrict__ A_log,
                          const float* __restrict__ Dp, const float* __restrict__ xz,
                          const float* __restrict__ hin, float* __restrict__ gated) {
    __shared__ float d_s[TSTEP][64];
    __shared__ float u_s[TSTEP][64];
    __shared__ float bc_s[TSTEP][32];
    __shared__ float y_s[TSTEP][64];
    int chunk = blockIdx.x, b = blockIdx.y, half = blockIdx.z;
    int tid = threadIdx.x;
    int dq = tid & 3;
    int dil = tid >> 2;
    int di = (half << 6) + dil;
    float4 al = *(const float4*)&A_log[(di << 4) + (dq << 2)];
    float Av[4] = { -expf(al.x), -expf(al.y), -expf(al.z), -expf(al.w) };
    float Dv = Dp[di];
    long ho = (((long)chunk * BB + b) << 11) + (di << 4) + (dq << 2);
    float4 h4 = *(const float4*)&hin[ho];
    float h[4] = { h4.x, h4.y, h4.z, h4.w };
    long t0 = ((long)b << 12) + (long)chunk * CLEN;

    int srow = tid >> 4, sc4 = (tid & 15) << 2;
    for (int tile = 0; tile < CLEN / TSTEP; ++tile) {
        __syncthreads();
        long ls = t0 + tile * TSTEP + srow;
        *(float4*)&d_s[srow][sc4] = *(const float4*)&delta[(ls << 7) + (half << 6) + sc4];
        *(float4*)&u_s[srow][sc4] = *(const float4*)&xi[(ls << 7) + (half << 6) + sc4];
        if (tid < 128) {
            int r2 = tid >> 3, cc = (tid & 7) << 2;
            long l2 = t0 + tile * TSTEP + r2;
            *(float4*)&bc_s[r2][cc] = *(const float4*)&xdbc[l2 * 36 + DTRK + cc];
        }
        __syncthreads();
        #pragma unroll
        for (int i = 0; i < TSTEP; ++i) {
            float d = d_s[i][dil];
            float u = u_s[i][dil];
            float du = d * u;
            float4 Bv = *(float4*)&bc_s[i][dq << 2];
            float4 Cv = *(float4*)&bc_s[i][16 + (dq << 2)];
            float a0 = __expf(d * Av[0]); h[0] = a0 * h[0] + du * Bv.x;
            float a1 = __expf(d * Av[1]); h[1] = a1 * h[1] + du * Bv.y;
            float a2 = __expf(d * Av[2]); h[2] = a2 * h[2] + du * Bv.z;
            float a3 = __expf(d * Av[3]); h[3] = a3 * h[3] + du * Bv.w;
            float yp = h[0] * Cv.x + h[1] * Cv.y + h[2] * Cv.z + h[3] * Cv.w;
            yp += __shfl_xor(yp, 1);
            yp += __shfl_xor(yp, 2);
            if (dq == 0)
                y_s[i][dil] = yp + u * Dv;
        }
        __syncthreads();
        {
            long l = t0 + tile * TSTEP + srow;
            float4 y4 = *(float4*)&y_s[srow][sc4];
            float4 z4 = *(const float4*)&xz[(l << 8) + DIM + (half << 6) + sc4];
            float4 o;
            o.x = y4.x * (z4.x / (1.f + __expf(-z4.x)));
            o.y = y4.y * (z4.y / (1.f + __expf(-z4.y)));
            o.z = y4.z * (z4.z / (1.f + __expf(-z4.z)));
            o.w = y4.w * (z4.w / (1.f + __expf(-z4.w)));
            *(float4*)&gated[(l << 7) + (half << 6) + sc4] = o;
        }
    }
}

// ---------------- out_proj GEMM (N=64,K=128) + residual: 4x4 register tile ----------------
__global__ __launch_bounds__(256, 1) void k_gemm_out2(const float* __restrict__ gated,
                                                      const float* __restrict__ wT,
                                                      float* __restrict__ tio) {
    __shared__ __align__(16) float ts[64 * 132];
    long m0 = (long)blockIdx.x << 6;
    int tid = threadIdx.x;
    int rg = tid >> 4;    // 16 groups x 4 rows
    int cg = tid & 15;    // 16 groups x 4 cols
    for (int i = tid; i < 8192; i += 256) {
        int r2 = i >> 7, k = i & 127;
        ts[r2 * 132 + k] = gated[(m0 << 7) + i];
    }
    __syncthreads();
    float acc[4][4] = {};
    int n0 = cg << 2;
    for (int k4 = 0; k4 < 32; ++k4) {
        float4 a[4];
        #pragma unroll
        for (int r2 = 0; r2 < 4; ++r2)
            a[r2] = *(const float4*)&ts[((rg << 2) + r2) * 132 + (k4 << 2)];
        #pragma unroll
        for (int kk = 0; kk < 4; ++kk) {
            const float* wr = wT + (((k4 << 2) + kk) << 6) + n0;
            float4 w0 = *(const float4*)&wr[0];
            #pragma unroll
            for (int r2 = 0; r2 < 4; ++r2) {
                float av = (kk == 0) ? a[r2].x : (kk == 1) ? a[r2].y
                         : (kk == 2) ? a[r2].z : a[r2].w;
                acc[r2][0] += av * w0.x; acc[r2][1] += av * w0.y;
                acc[r2][2] += av * w0.z; acc[r2][3] += av * w0.w;
            }
        }
    }
    #pragma unroll
    for (int r2 = 0; r2 < 4; ++r2) {
        long m = m0 + (rg << 2) + r2;
        float4 t0 = *(const float4*)&tio[(m << 6) + n0];
        t0.x += acc[r2][0]; t0.y += acc[r2][1];
        t0.z += acc[r2][2]; t0.w += acc[r2][3];
        *(float4*)&tio[(m << 6) + n0] = t0;
    }
}

// ---------------- dec1 weight transpose: [co][ci][tap] -> [ci][tap][co] ----------------
__global__ void k_prep_wdec1(const float* __restrict__ w, float* __restrict__ wT) {
    int idx = blockIdx.x * blockDim.x + threadIdx.x;   // 36864
    int co = idx & 63;
    int tap = (idx >> 6) % 9;
    int ci = idx / 576;
    wT[idx] = w[co * 576 + ci * 9 + tap];
}

// ---------------- dec2 weight transpose: [co][ci][tap9] -> [ci][co][tap12] ----------------
__global__ void k_prep_wdec2(const float* __restrict__ w, float* __restrict__ wT) {
    int idx = blockIdx.x * blockDim.x + threadIdx.x;
    if (idx >= 64 * NFC * 12) return;
    int tap = idx % 12;
    int t2 = idx / 12;
    int co = t2 % NFC;
    int ci = t2 / NFC;
    wT[idx] = (tap < 9) ? w[co * 576 + ci * 9 + tap] : 0.f;
}

// ---------------- decoder conv1: ci-split across waves, barrier-free K-loop ----------------
// grid (64 tiles, B), 256 thr. Wave wv: ci in [wv*16, wv*16+16). Thread: 8 px (row) x 8 co.
__global__ __launch_bounds__(256, 1) void k_dec1_new(const float* __restrict__ tin,
                                                     const float* __restrict__ wT,
                                                     const float* __restrict__ bias,
                                                     float* __restrict__ out) {
    __shared__ __align__(16) float x_s[64 * 132];   // [ci][10 rows * 12]
    __shared__ __align__(16) float w_s[4 * 4608];   // per-wave [8 ci][9 tap][64 co]; reused as partials
    int tile = blockIdx.x;
    int b = blockIdx.y;
    int ty0 = (tile >> 3) << 3;
    int tx0 = (tile & 7) << 3;
    int tid = threadIdx.x;
    int wv = tid >> 6;
    int lane = tid & 63;
    int r = lane >> 3;        // px row in tile
    int cg = lane & 7;        // co group (8 co)

    // stage x halo (10x10 px, 64 ci); coalesced read, 2-way-free LDS write (132 stride)
    for (int i = tid; i < 6400; i += 256) {
        int pl = i >> 6;
        int c = i & 63;
        int py = pl / 10, px = pl - py * 10;
        int ih = ty0 + py - 1, iw = tx0 + px - 1;
        float v = 0.f;
        if (ih >= 0 && ih < HH && iw >= 0 && iw < WWD)
            v = tin[(((long)((b << 12) + (ih << 6) + iw)) << 6) + c];
        x_s[c * 132 + py * 12 + px] = v;
    }
    // stage w chunk0 (per-wave private region)
    float* myw = &w_s[wv * 4608];
    const float* gw = wT + (wv * 16) * 576;
    float4 pref[18];
    #pragma unroll
    for (int i = 0; i < 18; ++i)
        pref[i] = *(const float4*)&gw[(i * 64 + lane) * 4];
    #pragma unroll
    for (int i = 0; i < 18; ++i)
        *(float4*)&myw[(i * 64 + lane) * 4] = pref[i];
    __syncthreads();

    float acc[8][8] = {};
    #pragma unroll
    for (int ch = 0; ch < 2; ++ch) {
        if (ch == 0) {
            const float* gw1 = wT + (wv * 16 + 8) * 576;
            #pragma unroll
            for (int i = 0; i < 18; ++i)
                pref[i] = *(const float4*)&gw1[(i * 64 + lane) * 4];
        }
        for (int cl = 0; cl < 8; ++cl) {
            int cib = wv * 16 + ch * 8 + cl;
            float xrow[3][10];
            #pragma unroll
            for (int kh = 0; kh < 3; ++kh) {
                const float* xr = &x_s[cib * 132 + (r + kh) * 12];
                float4 a0 = *(const float4*)&xr[0];
                float4 a1 = *(const float4*)&xr[4];
                float2 a2 = *(const float2*)&xr[8];
                xrow[kh][0] = a0.x; xrow[kh][1] = a0.y; xrow[kh][2] = a0.z; xrow[kh][3] = a0.w;
                xrow[kh][4] = a1.x; xrow[kh][5] = a1.y; xrow[kh][6] = a1.z; xrow[kh][7] = a1.w;
                xrow[kh][8] = a2.x; xrow[kh][9] = a2.y;
            }
            const float* wp = &myw[cl * 576];
            #pragma unroll
            for (int kh = 0; kh < 3; ++kh) {
                #pragma unroll
                for (int kw = 0; kw < 3; ++kw) {
                    const float* wp2 = wp + (kh * 3 + kw) * 64 + (cg << 3);
                    float4 wa = *(const float4*)&wp2[0];
                    float4 wb = *(const float4*)&wp2[4];
                    #pragma unroll
                    for (int j = 0; j < 8; ++j) {
                        float xv = xrow[kh][kw + j];
                        acc[j][0] += xv * wa.x; acc[j][1] += xv * wa.y;
                        acc[j][2] += xv * wa.z; acc[j][3] += xv * wa.w;
                        acc[j][4] += xv * wb.x; acc[j][5] += xv * wb.y;
                        acc[j][6] += xv * wb.z; acc[j][7] += xv * wb.w;
                    }
                }
            }
        }
        if (ch == 0) {
            // swap in chunk1 (own region; same-wave LDS ordering keeps RAW/WAR safe)
            #pragma unroll
            for (int i = 0; i < 18; ++i)
                *(float4*)&myw[(i * 64 + lane) * 4] = pref[i];
        }
    }

    // write partials into own (retired) w region: [lane][8px*8co], stride 68
    #pragma unroll
    for (int j = 0; j < 8; ++j) {
        *(float4*)&myw[lane * 68 + (j << 3)]     = make_float4(acc[j][0], acc[j][1], acc[j][2], acc[j][3]);
        *(float4*)&myw[lane * 68 + (j << 3) + 4] = make_float4(acc[j][4], acc[j][5], acc[j][6], acc[j][7]);
    }
    __syncthreads();

    // reduce 4 partials + bias, store: wave wv owns px rows 2wv..2wv+1; lane = co
    float bv = bias[lane];
    #pragma unroll
    for (int pp = 0; pp < 16; ++pp) {
        int pr = (wv << 1) + (pp >> 3);
        int pc = pp & 7;
        int ol = (pr << 3) + (lane >> 3);
        int ix = (pc << 3) + (lane & 7);
        float s = w_s[ol * 68 + ix] + w_s[4608 + ol * 68 + ix]
                + w_s[9216 + ol * 68 + ix] + w_s[13824 + ol * 68 + ix] + bv;
        out[(((long)((b << 12) + ((ty0 + pr) << 6) + tx0 + pc)) << 6) + lane] = s;
    }
}

// ------- decoder conv2 FUSED with BN+ReLU: pixel-major (B,4096,64) -> NCHW (B,10,64,64) -------
__global__ void k_dec2_fused(const float* __restrict__ src, const float* __restrict__ mv,
                             const float* __restrict__ g, const float* __restrict__ be,
                             const float* __restrict__ wT, const float* __restrict__ bias,
                             float* __restrict__ out) {
    __shared__ float x_s[64 * 101];
    __shared__ float w_s[64 * NFC * 12];
    __shared__ float sc_s[64];
    __shared__ float sh_s[64];
    int tile = blockIdx.x;
    int b = blockIdx.y;
    int ty0 = (tile >> 3) << 3;
    int tx0 = (tile & 7) << 3;
    int tid = threadIdx.x;

    if (tid < 64) {
        float m = mv[tid], v = mv[64 + tid];
        float s = g[tid] * rsqrtf(v + 1e-5f);
        sc_s[tid] = s;
        sh_s[tid] = be[tid] - m * s;
    }
    for (int i = tid; i < 64 * NFC * 12; i += 256)
        w_s[i] = wT[i];
    __syncthreads();

    for (int i = tid; i < 6400; i += 256) {
        int pl = i >> 6;
        int c = i & 63;
        int py = pl / 10, px = pl - py * 10;
        int ih = ty0 + py - 1, iw = tx0 + px - 1;
        float v = 0.f;
        if (ih >= 0 && ih < HH && iw >= 0 && iw < WWD) {
            v = src[((long)((b << 12) + (ih << 6) + iw)) * 64 + c];
            v = fmaxf(v * sc_s[c] + sh_s[c], 0.f);
        }
        x_s[c * 101 + pl] = v;
    }
    __syncthreads();

    int px = tid & 63;
    int py = px >> 3, pxx = px & 7;
    int cog = tid >> 6;
    float acc[3] = {0.f, 0.f, 0.f};
    int nco = (cog < 2) ? 3 : 2;

    for (int ci = 0; ci < 64; ++ci) {
        const float* xr = &x_s[ci * 101 + py * 10 + pxx];
        float xv[9];
        #pragma unroll
        for (int kh = 0; kh < 3; ++kh)
            #pragma unroll
            for (int kw = 0; kw < 3; ++kw)
                xv[kh * 3 + kw] = xr[kh * 10 + kw];
        #pragma unroll
        for (int j = 0; j < 3; ++j) {
            if (j >= nco) break;
            int co = cog + (j << 2);
            const float* wp = &w_s[(ci * NFC + co) * 12];
            float4 w0 = *(const float4*)&wp[0];
            float4 w1 = *(const float4*)&wp[4];
            float  w8 = wp[8];
            acc[j] += xv[0] * w0.x + xv[1] * w0.y + xv[2] * w0.z + xv[3] * w0.w
                    + xv[4] * w1.x + xv[5] * w1.y + xv[6] * w1.z + xv[7] * w1.w
                    + xv[8] * w8;
        }
    }
    int hw = ((ty0 + py) << 6) + tx0 + pxx;
    #pragma unroll
    for (int j = 0; j < 3; ++j) {
        if (j >= nco) break;
        int co = cog + (j << 2);
        out[((long)(b * NFC + co) << 12) + hw] = acc[j] + bias[co];
    }
}

extern "C" void kernel_launch(void* const* d_in, const int* in_sizes, int n_in,
                              void* d_out, int out_size, void* d_ws, size_t ws_size,
                              hipStream_t stream) {
    const float* x       = (const float*)d_in[0];
    const float* enc_w   = (const float*)d_in[1];
    const float* enc_b   = (const float*)d_in[2];
    const float* enc_g   = (const float*)d_in[3];
    const float* enc_be  = (const float*)d_in[4];
    const float* in_proj = (const float*)d_in[5];
    const float* conv_w  = (const float*)d_in[6];
    const float* conv_b  = (const float*)d_in[7];
    const float* x_proj  = (const float*)d_in[8];
    const float* dt_w    = (const float*)d_in[9];
    const float* dt_b    = (const float*)d_in[10];
    const float* A_log   = (const float*)d_in[11];
    const float* Dp      = (const float*)d_in[12];
    const float* out_prj = (const float*)d_in[13];
    const float* dec1_w  = (const float*)d_in[14];
    const float* dec1_b  = (const float*)d_in[15];
    const float* dec1_g  = (const float*)d_in[16];
    const float* dec1_be = (const float*)d_in[17];
    const float* dec2_w  = (const float*)d_in[18];
    const float* dec2_b  = (const float*)d_in[19];
    float* out = (float*)d_out;

    float* ws = (float*)d_ws;
    size_t off = 0;
    float* conv_buf  = ws + off; off += 1048576;  // enc/dec scratch; Pb/hin during layers
    float* mv        = ws + off; off += 128;
    float* pbuf      = ws + off; off += 8192;
    float* wT1       = ws + off; off += 36864;
    float* wT2       = ws + off; off += 7680;
    float* wTin      = ws + off; off += 65536;
    float* wTout     = ws + off; off += 32768;
    float* t_buf     = ws + off; off += 1048576;
    float* xz_buf    = ws + off; off += 4194304;
    float* xi_buf    = ws + off; off += 2097152;
    float* xdbc_buf  = ws + off; off += 589824;
    float* delta_buf = ws + off; off += 2097152;
    float* gated_buf = ws + off; off += 2097152;  // first 1M floats double as Sb
    (void)ws_size; (void)in_sizes; (void)n_in; (void)out_size;

    float* Pb = conv_buf;
    float* Sb = gated_buf;

    // prep
    k_prep_wt<<<384, 256, 0, stream>>>(in_proj, out_prj, wTin, wTout);
    k_prep_wdec1<<<144, 256, 0, stream>>>(dec1_w, wT1);
    k_prep_wdec2<<<30, 256, 0, stream>>>(dec2_w, wT2);

    // encoder
    k_enc_conv<<<4096, 256, 0, stream>>>(x, enc_w, enc_b, conv_buf);
    k_bn_stats<<<64, 256, 0, stream>>>(conv_buf, mv);
    k_bn_tr_seq<<<256, 256, 0, stream>>>(conv_buf, mv, enc_g, enc_be, t_buf);

    // mamba layers
    dim3 sg(NCHUNK, BB, 2);
    for (int i = 0; i < NLAYER; ++i) {
        k_gemm_in2<<<256, 256, 0, stream>>>(t_buf, wTin + i * 16384, xz_buf);
        k_xproj_fused<<<512, 256, 0, stream>>>(xz_buf, conv_w + i * DIM * DCN,
                                               conv_b + i * DIM, x_proj + i * 36 * DIM,
                                               dt_w + i * DIM * DTRK, dt_b + i * DIM,
                                               xi_buf, xdbc_buf, delta_buf);
        k_scan_p1<<<sg, 256, 0, stream>>>(delta_buf, xi_buf, xdbc_buf,
                                          A_log + i * DIM * DSN, Pb, Sb);
        k_scan_p2<<<32, 256, 0, stream>>>(Pb, Sb);
        k_scan_p3<<<sg, 256, 0, stream>>>(delta_buf, xi_buf, xdbc_buf,
                                          A_log + i * DIM * DSN, Dp + i * DIM,
                                          xz_buf, Pb, gated_buf);
        k_gemm_out2<<<256, 256, 0, stream>>>(gated_buf, wTout + i * 8192, t_buf);
    }

    // decoder
    dim3 dg1(64, BB);
    k_dec1_new<<<dg1, 256, 0, stream>>>(t_buf, wT1, dec1_b, conv_buf);
    k_bn_stats_pm_part<<<64, 256, 0, stream>>>(conv_buf, pbuf);
    k_bn_stats_pm_fin<<<1, 64, 0, stream>>>(pbuf, mv);
    k_dec2_fused<<<dg1, 256, 0, stream>>>(conv_buf, mv, dec1_g, dec1_be, wT2, dec2_b, out);
}